// Round 3
// baseline (503.122 us; speedup 1.0000x reference)
//
#include <hip/hip_runtime.h>
#include <hip/hip_fp16.h>
#include <cstdint>
#include <cstddef>

#define NHEADS 4
#define OUT_C 32
#define HC 128          // NHEADS*OUT_C
#define IN_CH 128
#define NEG_SLOPE 0.2f

static inline size_t align256(size_t v) { return (v + 255) & ~(size_t)255; }

__device__ __forceinline__ float lrelu(float v) { return v > 0.f ? v : NEG_SLOPE * v; }

__device__ __forceinline__ float wred_sum(float v) {
    v += __shfl_xor(v, 1);
    v += __shfl_xor(v, 2);
    v += __shfl_xor(v, 4);
    v += __shfl_xor(v, 8);
    v += __shfl_xor(v, 16);
    v += __shfl_xor(v, 32);
    return v;
}

__device__ __forceinline__ uint2 pack_half4(float4 p) {
    __half2 h01 = __floats2half2_rn(p.x, p.y);
    __half2 h23 = __floats2half2_rn(p.z, p.w);
    uint2 u;
    u.x = *reinterpret_cast<unsigned int*>(&h01);
    u.y = *reinterpret_cast<unsigned int*>(&h23);
    return u;
}
__device__ __forceinline__ float4 unpack_half4(uint2 u) {
    __half2 h01 = *reinterpret_cast<__half2*>(&u.x);
    __half2 h23 = *reinterpret_cast<__half2*>(&u.y);
    float2 f01 = __half22float2(h01);
    float2 f23 = __half22float2(h23);
    return make_float4(f01.x, f01.y, f23.x, f23.y);
}

// ---------------------------------------------------------------------------
// Detect whether edge_index is int64 (odd 4B words all zero for values<2^31)
// or int32. Writes flag=1 for int64, 0 for int32.
__global__ void detect_dtype(const int* __restrict__ ei, int* __restrict__ flag) {
    __shared__ int red[256];
    int t = threadIdx.x;
    int acc = 0;
    for (int i = t; i < 1024; i += 256) acc |= ei[2 * i + 1];
    red[t] = acc;
    __syncthreads();
    for (int s = 128; s > 0; s >>= 1) {
        if (t < s) red[t] |= red[t + s];
        __syncthreads();
    }
    if (t == 0) *flag = (red[0] == 0) ? 1 : 0;
}

// ---------------------------------------------------------------------------
// W [128 out][128 in] -> wt [k][o] transposed copy (tiny)
__global__ void wtrans(const float* __restrict__ W, float* __restrict__ wt) {
    int idx = blockIdx.x * 256 + threadIdx.x;
    if (idx < 128 * 128) {
        int k = idx >> 7, o = idx & 127;
        wt[idx] = W[o * 128 + k];
    }
}

// ---------------------------------------------------------------------------
// h[n][128] = x[n][128] @ W^T (fp32 VALU GEMM, 64 rows/block)
// Fused epilogue: a_src[n][4], a_dst[n][4] attention logits.
__global__ __launch_bounds__(256) void gemm_h(const float* __restrict__ x,
                                              const float* __restrict__ wtg,
                                              const float* __restrict__ att_src,
                                              const float* __restrict__ att_dst,
                                              float* __restrict__ h,
                                              float* __restrict__ a_src,
                                              float* __restrict__ a_dst, int n) {
    __shared__ float xs[64][132];   // +4 pad: kills bank conflicts on row reads
    __shared__ float wt[32][132];
    int tid = threadIdx.x;
    int rowbase = blockIdx.x << 6;
    const float4* x4 = (const float4*)x;
#pragma unroll
    for (int i = 0; i < 8; ++i) {
        int f4 = (i << 8) + tid;          // 0..2047
        int r = f4 >> 5, cc = (f4 & 31) << 2;
        int row = rowbase + r;
        if (row >= n) row = n - 1;        // clamp; stores guarded below
        float4 v = x4[((size_t)row << 5) + (cc >> 2)];
        *(float4*)&xs[r][cc] = v;
    }
    int rg = tid >> 4, cg = tid & 15;     // 16 row-groups x 16 col-groups
    float acc[4][8];
#pragma unroll
    for (int a = 0; a < 4; ++a)
#pragma unroll
        for (int b = 0; b < 8; ++b) acc[a][b] = 0.f;

    for (int kc = 0; kc < 128; kc += 32) {
        __syncthreads();
        const float4* wg4 = (const float4*)(wtg + (size_t)kc * 128);
#pragma unroll
        for (int i = 0; i < 4; ++i) {
            int f4 = (i << 8) + tid;      // 0..1023
            int kk = f4 >> 5, oo = (f4 & 31) << 2;
            *(float4*)&wt[kk][oo] = wg4[f4];
        }
        __syncthreads();
#pragma unroll
        for (int k = 0; k < 32; k += 4) {
            float xk[4][4];
#pragma unroll
            for (int rr = 0; rr < 4; ++rr) {
                float4 t = *(const float4*)&xs[(rg << 2) + rr][kc + k];
                xk[rr][0] = t.x; xk[rr][1] = t.y; xk[rr][2] = t.z; xk[rr][3] = t.w;
            }
#pragma unroll
            for (int kk = 0; kk < 4; ++kk) {
                float4 wa = *(const float4*)&wt[k + kk][cg << 3];
                float4 wb = *(const float4*)&wt[k + kk][(cg << 3) + 4];
                float wv[8] = {wa.x, wa.y, wa.z, wa.w, wb.x, wb.y, wb.z, wb.w};
#pragma unroll
                for (int rr = 0; rr < 4; ++rr)
#pragma unroll
                    for (int jj = 0; jj < 8; ++jj)
                        acc[rr][jj] = fmaf(xk[rr][kk], wv[jj], acc[rr][jj]);
            }
        }
    }
#pragma unroll
    for (int rr = 0; rr < 4; ++rr) {
        int row = rowbase + (rg << 2) + rr;
        if (row < n) {
            float4 o1 = {acc[rr][0], acc[rr][1], acc[rr][2], acc[rr][3]};
            float4 o2 = {acc[rr][4], acc[rr][5], acc[rr][6], acc[rr][7]};
            float4* hp = (float4*)(h + ((size_t)row << 7) + (cg << 3));
            hp[0] = o1;
            hp[1] = o2;
        }
    }
    // ---- fused attention-logit epilogue ----
    // thread covers cols c0 = cg*8 .. +7, all within head = cg>>2.
    int head = cg >> 2;
    int coff = (head << 5) + ((cg & 3) << 3);
    float4 sa1 = *(const float4*)(att_src + coff);
    float4 sa2 = *(const float4*)(att_src + coff + 4);
    float4 da1 = *(const float4*)(att_dst + coff);
    float4 da2 = *(const float4*)(att_dst + coff + 4);
    float av[8] = {sa1.x, sa1.y, sa1.z, sa1.w, sa2.x, sa2.y, sa2.z, sa2.w};
    float bv[8] = {da1.x, da1.y, da1.z, da1.w, da2.x, da2.y, da2.z, da2.w};
#pragma unroll
    for (int rr = 0; rr < 4; ++rr) {
        float ps = 0.f, pd = 0.f;
#pragma unroll
        for (int jj = 0; jj < 8; ++jj) {
            ps = fmaf(acc[rr][jj], av[jj], ps);
            pd = fmaf(acc[rr][jj], bv[jj], pd);
        }
        ps += __shfl_xor(ps, 1);
        ps += __shfl_xor(ps, 2);
        pd += __shfl_xor(pd, 1);
        pd += __shfl_xor(pd, 2);
        int row = rowbase + (rg << 2) + rr;
        if ((cg & 3) == 0 && row < n) {
            a_src[(row << 2) + head] = ps;
            a_dst[(row << 2) + head] = pd;
        }
    }
}

// ---------------------------------------------------------------------------
// histogram of dst (edges only; self-loops added as +1 in scan)
__global__ void hist(const int* __restrict__ ei, const int* __restrict__ flag,
                     int* __restrict__ deg, int E) {
    int i = blockIdx.x * 256 + threadIdx.x;
    if (i >= E) return;
    int f64 = *flag;
    int d = f64 ? ei[2 * ((size_t)E + i)] : ei[(size_t)E + i];
    atomicAdd(&deg[d], 1);
}

// chunked exclusive scan, chunk=2048 (256 thr x 8)
__global__ void scan1(const int* __restrict__ deg, int* __restrict__ off,
                      int* __restrict__ tot, int n) {
    __shared__ int ts[256];
    int t = threadIdx.x;
    int i0 = (blockIdx.x << 11) + (t << 3);
    int pref[8];
    int sum = 0;
#pragma unroll
    for (int j = 0; j < 8; ++j) {
        int i = i0 + j;
        int v = (i < n) ? (deg[i] + 1) : 0;  // +1 = self loop
        pref[j] = sum;
        sum += v;
    }
    ts[t] = sum;
    __syncthreads();
    int run = sum;
    for (int d = 1; d < 256; d <<= 1) {
        int o = (t >= d) ? ts[t - d] : 0;
        __syncthreads();
        run += o;
        ts[t] = run;
        __syncthreads();
    }
    int excl = run - sum;
#pragma unroll
    for (int j = 0; j < 8; ++j) {
        int i = i0 + j;
        if (i < n) off[i] = excl + pref[j];
    }
    if (t == 255) tot[blockIdx.x] = run;
}

__global__ void scan2(const int* __restrict__ tot, int* __restrict__ cbase, int nc) {
    int lane = threadIdx.x;  // 64 threads, 1 wave
    int carry = 0;
    for (int b = 0; b < nc; b += 64) {
        int i = b + lane;
        int v = (i < nc) ? tot[i] : 0;
        int orig = v;
        for (int d = 1; d < 64; d <<= 1) {
            int u = __shfl_up(v, d);
            if (lane >= d) v += u;
        }
        if (i < nc) cbase[i] = carry + v - orig;
        carry += __shfl(v, 63);
    }
}

__global__ void finalize(int* __restrict__ off, const int* __restrict__ cbase, int n, int E) {
    int i = blockIdx.x * 256 + threadIdx.x;
    if (i < n) off[i] += cbase[i >> 11];
    else if (i == n) off[n] = E + n;
}

// ---------------------------------------------------------------------------
// Counting-sort scatter + fused alpha computation:
// p = exp(lrelu(a_src[s] + a_dst[d])) stored as half4 at the sorted slot.
// No max-subtraction: logits are bounded (|a|<~5), exp safe in fp16 range;
// softmax is shift-invariant so result is identical up to rounding.
__global__ void scatter(const int* __restrict__ ei, const int* __restrict__ flag,
                        const int* __restrict__ off, int* __restrict__ cursor,
                        int* __restrict__ sorted, uint2* __restrict__ alphaH,
                        const float* __restrict__ a_src, const float* __restrict__ a_dst,
                        int E, int n) {
    int i = blockIdx.x * 256 + threadIdx.x;
    if (i >= E + n) return;
    int f64 = *flag;
    int s, d;
    if (i < E) {
        if (f64) { s = ei[2 * (size_t)i]; d = ei[2 * ((size_t)E + i)]; }
        else     { s = ei[i];             d = ei[(size_t)E + i]; }
    } else {
        s = d = i - E;  // self loop
    }
    int pos = off[d] + atomicAdd(&cursor[d], 1);
    sorted[pos] = s;
    float4 as = ((const float4*)a_src)[s];
    float4 ad = ((const float4*)a_dst)[d];
    float4 p;
    p.x = __expf(lrelu(as.x + ad.x));
    p.y = __expf(lrelu(as.y + ad.y));
    p.z = __expf(lrelu(as.z + ad.z));
    p.w = __expf(lrelu(as.w + ad.w));
    alphaH[pos] = pack_half4(p);
}

// ---------------------------------------------------------------------------
// Gather-accumulate for one half-wave (lane L=lane&31 owns ch 4L..4L+3).
// Edges for this half: half, half+2, ... ; unroll x4 -> 4 gathers in flight.
__device__ __forceinline__ void accum_half(const int* ssrc, const float* sal,
                                           const float* __restrict__ h,
                                           int deg, int half, int L, int head,
                                           float4& acc) {
    float4 a0 = {0, 0, 0, 0}, a1 = {0, 0, 0, 0}, a2 = {0, 0, 0, 0}, a3 = {0, 0, 0, 0};
    int j = half;
    for (; j + 6 < deg; j += 8) {
        int s0 = ssrc[j], s1 = ssrc[j + 2], s2 = ssrc[j + 4], s3 = ssrc[j + 6];
        float w0 = sal[(j << 2) + head];
        float w1 = sal[((j + 2) << 2) + head];
        float w2 = sal[((j + 4) << 2) + head];
        float w3 = sal[((j + 6) << 2) + head];
        float4 v0 = *(const float4*)(h + ((size_t)s0 << 7) + (L << 2));
        float4 v1 = *(const float4*)(h + ((size_t)s1 << 7) + (L << 2));
        float4 v2 = *(const float4*)(h + ((size_t)s2 << 7) + (L << 2));
        float4 v3 = *(const float4*)(h + ((size_t)s3 << 7) + (L << 2));
        a0.x = fmaf(w0, v0.x, a0.x); a0.y = fmaf(w0, v0.y, a0.y);
        a0.z = fmaf(w0, v0.z, a0.z); a0.w = fmaf(w0, v0.w, a0.w);
        a1.x = fmaf(w1, v1.x, a1.x); a1.y = fmaf(w1, v1.y, a1.y);
        a1.z = fmaf(w1, v1.z, a1.z); a1.w = fmaf(w1, v1.w, a1.w);
        a2.x = fmaf(w2, v2.x, a2.x); a2.y = fmaf(w2, v2.y, a2.y);
        a2.z = fmaf(w2, v2.z, a2.z); a2.w = fmaf(w2, v2.w, a2.w);
        a3.x = fmaf(w3, v3.x, a3.x); a3.y = fmaf(w3, v3.y, a3.y);
        a3.z = fmaf(w3, v3.z, a3.z); a3.w = fmaf(w3, v3.w, a3.w);
    }
    for (; j < deg; j += 2) {
        int s0 = ssrc[j];
        float w0 = sal[(j << 2) + head];
        float4 v0 = *(const float4*)(h + ((size_t)s0 << 7) + (L << 2));
        a0.x = fmaf(w0, v0.x, a0.x); a0.y = fmaf(w0, v0.y, a0.y);
        a0.z = fmaf(w0, v0.z, a0.z); a0.w = fmaf(w0, v0.w, a0.w);
    }
    acc.x += a0.x + a1.x + a2.x + a3.x;
    acc.y += a0.y + a1.y + a2.y + a3.y;
    acc.z += a0.z + a1.z + a2.z + a3.z;
    acc.w += a0.w + a1.w + a2.w + a3.w;
}

// One wave per destination node: read precomputed alphas (coalesced),
// normalize (sum only -- alphas are pre-exp'd), gather-aggregate h.
__global__ __launch_bounds__(256) void aggregate(const float* __restrict__ h,
                                                 const int* __restrict__ sorted,
                                                 const uint2* __restrict__ alphaH,
                                                 const int* __restrict__ off,
                                                 const float* __restrict__ bias,
                                                 float* __restrict__ agg, int n) {
    __shared__ int sh_src[4][64];
    __shared__ float sh_al[4][256];    // [edge][head]
    int wslot = threadIdx.x >> 6;
    int lane = threadIdx.x & 63;
    int wid = blockIdx.x * (blockDim.x >> 6) + wslot;
    int nw = gridDim.x * (blockDim.x >> 6);
    int L = lane & 31, half = lane >> 5, head = L >> 3;
    float4 b4 = ((const float4*)bias)[L];
    int* ssrc = sh_src[wslot];
    float* sal = sh_al[wslot];

    for (int node = wid; node < n; node += nw) {
        int start = off[node], end = off[node + 1];
        int deg = end - start;          // >= 1 (self loop)
        float4 acc = {0.f, 0.f, 0.f, 0.f};

        if (deg <= 64) {
            bool v = lane < deg;
            int idx = start + (v ? lane : 0);
            int s = sorted[idx];
            float4 p = unpack_half4(alphaH[idx]);
            if (!v) p = make_float4(0.f, 0.f, 0.f, 0.f);
            float s0 = wred_sum(p.x), s1 = wred_sum(p.y);
            float s2 = wred_sum(p.z), s3 = wred_sum(p.w);
            float4 al = {p.x / s0, p.y / s1, p.z / s2, p.w / s3};
            ssrc[lane] = s;
            *(float4*)&sal[lane << 2] = al;
            asm volatile("s_waitcnt lgkmcnt(0)" ::: "memory");
            accum_half(ssrc, sal, h, deg, half, L, head, acc);
            asm volatile("" ::: "memory");
        } else {
            // chunked path (rare: mean degree ~17)
            float4 ps = {0.f, 0.f, 0.f, 0.f};
            for (int bb = 0; bb < deg; bb += 64) {
                int i = bb + lane;
                bool v = i < deg;
                int idx = start + (v ? i : 0);
                float4 p = unpack_half4(alphaH[idx]);
                if (v) { ps.x += p.x; ps.y += p.y; ps.z += p.z; ps.w += p.w; }
            }
            float s0 = wred_sum(ps.x), s1 = wred_sum(ps.y);
            float s2 = wred_sum(ps.z), s3 = wred_sum(ps.w);
            float i0 = 1.f / s0, i1 = 1.f / s1, i2 = 1.f / s2, i3 = 1.f / s3;
            for (int bb = 0; bb < deg; bb += 64) {
                int i = bb + lane;
                bool v = i < deg;
                int idx = start + (v ? i : 0);
                int s = sorted[idx];
                float4 p = unpack_half4(alphaH[idx]);
                float4 al = {p.x * i0, p.y * i1, p.z * i2, p.w * i3};
                ssrc[lane] = s;
                *(float4*)&sal[lane << 2] = al;
                asm volatile("s_waitcnt lgkmcnt(0)" ::: "memory");
                int cl = deg - bb;
                if (cl > 64) cl = 64;
                accum_half(ssrc, sal, h, cl, half, L, head, acc);
                asm volatile("" ::: "memory");
            }
        }
        acc.x += __shfl_xor(acc.x, 32);
        acc.y += __shfl_xor(acc.y, 32);
        acc.z += __shfl_xor(acc.z, 32);
        acc.w += __shfl_xor(acc.w, 32);
        if (lane < 32) {
            float4 res = {acc.x + b4.x, acc.y + b4.y, acc.z + b4.z, acc.w + b4.w};
            *(float4*)(agg + ((size_t)node << 7) + (L << 2)) = res;
        }
    }
}

// ---------------------------------------------------------------------------
// out[n][32] = elu(agg[n][128] @ W_lin^T + b_lin)
__global__ __launch_bounds__(256) void proj(const float* __restrict__ agg,
                                            const float* __restrict__ W_lin,
                                            const float* __restrict__ b_lin,
                                            float* __restrict__ out, int n) {
    __shared__ float xs[64][132];
    __shared__ float wt[128][36];   // wt[k][o]
    int tid = threadIdx.x;
    const float4* w4 = (const float4*)W_lin;
#pragma unroll
    for (int i = 0; i < 4; ++i) {
        int f4 = (i << 8) + tid;          // 0..1023
        int o = f4 >> 5, kk = (f4 & 31) << 2;
        float4 w = w4[f4];
        wt[kk][o] = w.x;
        wt[kk + 1][o] = w.y;
        wt[kk + 2][o] = w.z;
        wt[kk + 3][o] = w.w;
    }
    int rowbase = blockIdx.x << 6;
    const float4* a4 = (const float4*)agg;
#pragma unroll
    for (int i = 0; i < 8; ++i) {
        int f4 = (i << 8) + tid;          // 0..2047
        int r = f4 >> 5, cc = (f4 & 31) << 2;
        int row = rowbase + r;
        if (row >= n) row = n - 1;
        *(float4*)&xs[r][cc] = a4[((size_t)row << 5) + (cc >> 2)];
    }
    __syncthreads();
    int r = tid >> 2, cg = tid & 3, c0 = cg << 3;
    float acc[8];
#pragma unroll
    for (int j = 0; j < 8; ++j) acc[j] = 0.f;
    for (int k = 0; k < 128; k += 4) {
        float4 xv = *(const float4*)&xs[r][k];
        float xk[4] = {xv.x, xv.y, xv.z, xv.w};
#pragma unroll
        for (int kk = 0; kk < 4; ++kk) {
            float4 wa = *(const float4*)&wt[k + kk][c0];
            float4 wb = *(const float4*)&wt[k + kk][c0 + 4];
            acc[0] = fmaf(xk[kk], wa.x, acc[0]);
            acc[1] = fmaf(xk[kk], wa.y, acc[1]);
            acc[2] = fmaf(xk[kk], wa.z, acc[2]);
            acc[3] = fmaf(xk[kk], wa.w, acc[3]);
            acc[4] = fmaf(xk[kk], wb.x, acc[4]);
            acc[5] = fmaf(xk[kk], wb.y, acc[5]);
            acc[6] = fmaf(xk[kk], wb.z, acc[6]);
            acc[7] = fmaf(xk[kk], wb.w, acc[7]);
        }
    }
    int row = rowbase + r;
    if (row < n) {
        float res[8];
#pragma unroll
        for (int j = 0; j < 8; ++j) {
            float v = acc[j] + b_lin[c0 + j];
            res[j] = v > 0.f ? v : (__expf(v) - 1.f);
        }
        float4* op = (float4*)(out + (size_t)row * 32 + c0);
        op[0] = make_float4(res[0], res[1], res[2], res[3]);
        op[1] = make_float4(res[4], res[5], res[6], res[7]);
    }
}

// ---------------------------------------------------------------------------
extern "C" void kernel_launch(void* const* d_in, const int* in_sizes, int n_in,
                              void* d_out, int out_size, void* d_ws, size_t ws_size,
                              hipStream_t stream) {
    const float* x = (const float*)d_in[0];
    const int* ei = (const int*)d_in[1];
    const float* W = (const float*)d_in[2];
    const float* att_src = (const float*)d_in[3];
    const float* att_dst = (const float*)d_in[4];
    const float* bias_conv = (const float*)d_in[5];
    const float* W_lin = (const float*)d_in[6];
    const float* b_lin = (const float*)d_in[7];
    int n = in_sizes[0] / IN_CH;
    int E = in_sizes[1] / 2;

    char* ws = (char*)d_ws;
    size_t o = 0;
    auto alloc = [&](size_t bytes) { char* p = ws + o; o = align256(o + bytes); return p; };
    float* h       = (float*)alloc((size_t)n * HC * 4);
    float* agg     = (float*)alloc((size_t)n * HC * 4);
    float* wtg     = (float*)alloc(128 * 128 * 4);
    float* a_src   = (float*)alloc((size_t)n * NHEADS * 4);
    float* a_dst   = (float*)alloc((size_t)n * NHEADS * 4);
    int* deg       = (int*)alloc((size_t)n * 4);
    int* cursor    = (int*)alloc((size_t)n * 4);
    int* off       = (int*)alloc(((size_t)n + 1) * 4);
    int* chunkTot  = (int*)alloc(256 * 4);
    int* chunkBase = (int*)alloc(256 * 4);
    int* flag      = (int*)alloc(256);
    int* sorted    = (int*)alloc((size_t)(E + n + 64) * 4);
    uint2* alphaH  = (uint2*)alloc((size_t)(E + n + 64) * 8);

    hipMemsetAsync(deg, 0, (size_t)n * 4, stream);
    hipMemsetAsync(cursor, 0, (size_t)n * 4, stream);

    detect_dtype<<<1, 256, 0, stream>>>(ei, flag);
    wtrans<<<64, 256, 0, stream>>>(W, wtg);
    gemm_h<<<(n + 63) / 64, 256, 0, stream>>>(x, wtg, att_src, att_dst, h, a_src, a_dst, n);
    hist<<<(E + 255) / 256, 256, 0, stream>>>(ei, flag, deg, E);
    int nchunks = (n + 2047) / 2048;
    scan1<<<nchunks, 256, 0, stream>>>(deg, off, chunkTot, n);
    scan2<<<1, 64, 0, stream>>>(chunkTot, chunkBase, nchunks);
    finalize<<<(n + 1 + 255) / 256, 256, 0, stream>>>(off, chunkBase, n, E);
    scatter<<<(E + n + 255) / 256, 256, 0, stream>>>(ei, flag, off, cursor, sorted, alphaH,
                                                     a_src, a_dst, E, n);
    aggregate<<<2048, 256, 0, stream>>>(h, sorted, alphaH, off, bias_conv, agg, n);
    proj<<<(n + 63) / 64, 256, 0, stream>>>(agg, W_lin, b_lin, (float*)d_out, n);
}

// Round 4
// 423.783 us; speedup vs baseline: 1.1872x; 1.1872x over previous
//
#include <hip/hip_runtime.h>
#include <hip/hip_fp16.h>
#include <cstdint>
#include <cstddef>

#define NHEADS 4
#define OUT_C 32
#define HC 128          // NHEADS*OUT_C
#define IN_CH 128
#define NEG_SLOPE 0.2f

static inline size_t align256(size_t v) { return (v + 255) & ~(size_t)255; }

__device__ __forceinline__ float lrelu(float v) { return v > 0.f ? v : NEG_SLOPE * v; }

__device__ __forceinline__ float wred_sum(float v) {
    v += __shfl_xor(v, 1);
    v += __shfl_xor(v, 2);
    v += __shfl_xor(v, 4);
    v += __shfl_xor(v, 8);
    v += __shfl_xor(v, 16);
    v += __shfl_xor(v, 32);
    return v;
}

__device__ __forceinline__ unsigned int pack_h2(float a, float b) {
    __half2 h = __floats2half2_rn(a, b);
    return *reinterpret_cast<unsigned int*>(&h);
}
__device__ __forceinline__ float2 unpack_h2(unsigned int u) {
    __half2 h = *reinterpret_cast<__half2*>(&u);
    return __half22float2(h);
}

// ---------------------------------------------------------------------------
// Detect whether edge_index is int64 (odd 4B words all zero for values<2^31)
// or int32. Writes flag=1 for int64, 0 for int32.
__global__ void detect_dtype(const int* __restrict__ ei, int* __restrict__ flag) {
    __shared__ int red[256];
    int t = threadIdx.x;
    int acc = 0;
    for (int i = t; i < 1024; i += 256) acc |= ei[2 * i + 1];
    red[t] = acc;
    __syncthreads();
    for (int s = 128; s > 0; s >>= 1) {
        if (t < s) red[t] |= red[t + s];
        __syncthreads();
    }
    if (t == 0) *flag = (red[0] == 0) ? 1 : 0;
}

// ---------------------------------------------------------------------------
// W [128 out][128 in] -> wt [k][o] transposed copy (tiny)
__global__ void wtrans(const float* __restrict__ W, float* __restrict__ wt) {
    int idx = blockIdx.x * 256 + threadIdx.x;
    if (idx < 128 * 128) {
        int k = idx >> 7, o = idx & 127;
        wt[idx] = W[o * 128 + k];
    }
}

// ---------------------------------------------------------------------------
// h[n][128] (fp16) = x[n][128] @ W^T (fp32 VALU GEMM, 64 rows/block)
// Fused epilogue: a_src[n][4], a_dst[n][4] attention logits (fp32).
__global__ __launch_bounds__(256) void gemm_h(const float* __restrict__ x,
                                              const float* __restrict__ wtg,
                                              const float* __restrict__ att_src,
                                              const float* __restrict__ att_dst,
                                              __half* __restrict__ h,
                                              float* __restrict__ a_src,
                                              float* __restrict__ a_dst, int n) {
    __shared__ float xs[64][132];   // +4 pad: kills bank conflicts on row reads
    __shared__ float wt[32][132];
    int tid = threadIdx.x;
    int rowbase = blockIdx.x << 6;
    const float4* x4 = (const float4*)x;
#pragma unroll
    for (int i = 0; i < 8; ++i) {
        int f4 = (i << 8) + tid;          // 0..2047
        int r = f4 >> 5, cc = (f4 & 31) << 2;
        int row = rowbase + r;
        if (row >= n) row = n - 1;        // clamp; stores guarded below
        float4 v = x4[((size_t)row << 5) + (cc >> 2)];
        *(float4*)&xs[r][cc] = v;
    }
    int rg = tid >> 4, cg = tid & 15;     // 16 row-groups x 16 col-groups
    float acc[4][8];
#pragma unroll
    for (int a = 0; a < 4; ++a)
#pragma unroll
        for (int b = 0; b < 8; ++b) acc[a][b] = 0.f;

    for (int kc = 0; kc < 128; kc += 32) {
        __syncthreads();
        const float4* wg4 = (const float4*)(wtg + (size_t)kc * 128);
#pragma unroll
        for (int i = 0; i < 4; ++i) {
            int f4 = (i << 8) + tid;      // 0..1023
            int kk = f4 >> 5, oo = (f4 & 31) << 2;
            *(float4*)&wt[kk][oo] = wg4[f4];
        }
        __syncthreads();
#pragma unroll
        for (int k = 0; k < 32; k += 4) {
            float xk[4][4];
#pragma unroll
            for (int rr = 0; rr < 4; ++rr) {
                float4 t = *(const float4*)&xs[(rg << 2) + rr][kc + k];
                xk[rr][0] = t.x; xk[rr][1] = t.y; xk[rr][2] = t.z; xk[rr][3] = t.w;
            }
#pragma unroll
            for (int kk = 0; kk < 4; ++kk) {
                float4 wa = *(const float4*)&wt[k + kk][cg << 3];
                float4 wb = *(const float4*)&wt[k + kk][(cg << 3) + 4];
                float wv[8] = {wa.x, wa.y, wa.z, wa.w, wb.x, wb.y, wb.z, wb.w};
#pragma unroll
                for (int rr = 0; rr < 4; ++rr)
#pragma unroll
                    for (int jj = 0; jj < 8; ++jj)
                        acc[rr][jj] = fmaf(xk[rr][kk], wv[jj], acc[rr][jj]);
            }
        }
    }
#pragma unroll
    for (int rr = 0; rr < 4; ++rr) {
        int row = rowbase + (rg << 2) + rr;
        if (row < n) {
            uint4 u;
            u.x = pack_h2(acc[rr][0], acc[rr][1]);
            u.y = pack_h2(acc[rr][2], acc[rr][3]);
            u.z = pack_h2(acc[rr][4], acc[rr][5]);
            u.w = pack_h2(acc[rr][6], acc[rr][7]);
            *(uint4*)(h + ((size_t)row << 7) + (cg << 3)) = u;
        }
    }
    // ---- fused attention-logit epilogue ----
    int head = cg >> 2;
    int coff = (head << 5) + ((cg & 3) << 3);
    float4 sa1 = *(const float4*)(att_src + coff);
    float4 sa2 = *(const float4*)(att_src + coff + 4);
    float4 da1 = *(const float4*)(att_dst + coff);
    float4 da2 = *(const float4*)(att_dst + coff + 4);
    float av[8] = {sa1.x, sa1.y, sa1.z, sa1.w, sa2.x, sa2.y, sa2.z, sa2.w};
    float bv[8] = {da1.x, da1.y, da1.z, da1.w, da2.x, da2.y, da2.z, da2.w};
#pragma unroll
    for (int rr = 0; rr < 4; ++rr) {
        float ps = 0.f, pd = 0.f;
#pragma unroll
        for (int jj = 0; jj < 8; ++jj) {
            ps = fmaf(acc[rr][jj], av[jj], ps);
            pd = fmaf(acc[rr][jj], bv[jj], pd);
        }
        ps += __shfl_xor(ps, 1);
        ps += __shfl_xor(ps, 2);
        pd += __shfl_xor(pd, 1);
        pd += __shfl_xor(pd, 2);
        int row = rowbase + (rg << 2) + rr;
        if ((cg & 3) == 0 && row < n) {
            a_src[(row << 2) + head] = ps;
            a_dst[(row << 2) + head] = pd;
        }
    }
}

// ---------------------------------------------------------------------------
// histogram of dst (edges only; self-loops added as +1 in scan)
__global__ void hist(const int* __restrict__ ei, const int* __restrict__ flag,
                     int* __restrict__ deg, int E) {
    int i = blockIdx.x * 256 + threadIdx.x;
    if (i >= E) return;
    int f64 = *flag;
    int d = f64 ? ei[2 * ((size_t)E + i)] : ei[(size_t)E + i];
    atomicAdd(&deg[d], 1);
}

// chunked exclusive scan, chunk=2048 (256 thr x 8)
__global__ void scan1(const int* __restrict__ deg, int* __restrict__ off,
                      int* __restrict__ tot, int n) {
    __shared__ int ts[256];
    int t = threadIdx.x;
    int i0 = (blockIdx.x << 11) + (t << 3);
    int pref[8];
    int sum = 0;
#pragma unroll
    for (int j = 0; j < 8; ++j) {
        int i = i0 + j;
        int v = (i < n) ? (deg[i] + 1) : 0;  // +1 = self loop
        pref[j] = sum;
        sum += v;
    }
    ts[t] = sum;
    __syncthreads();
    int run = sum;
    for (int d = 1; d < 256; d <<= 1) {
        int o = (t >= d) ? ts[t - d] : 0;
        __syncthreads();
        run += o;
        ts[t] = run;
        __syncthreads();
    }
    int excl = run - sum;
#pragma unroll
    for (int j = 0; j < 8; ++j) {
        int i = i0 + j;
        if (i < n) off[i] = excl + pref[j];
    }
    if (t == 255) tot[blockIdx.x] = run;
}

__global__ void scan2(const int* __restrict__ tot, int* __restrict__ cbase, int nc) {
    int lane = threadIdx.x;  // 64 threads, 1 wave
    int carry = 0;
    for (int b = 0; b < nc; b += 64) {
        int i = b + lane;
        int v = (i < nc) ? tot[i] : 0;
        int orig = v;
        for (int d = 1; d < 64; d <<= 1) {
            int u = __shfl_up(v, d);
            if (lane >= d) v += u;
        }
        if (i < nc) cbase[i] = carry + v - orig;
        carry += __shfl(v, 63);
    }
}

__global__ void finalize(int* __restrict__ off, const int* __restrict__ cbase, int n, int E) {
    int i = blockIdx.x * 256 + threadIdx.x;
    if (i < n) off[i] += cbase[i >> 11];
    else if (i == n) off[n] = E + n;
}

// ---------------------------------------------------------------------------
// Counting-sort scatter + fused alpha computation. One 16B record per edge:
// {src, half2(p0,p1), half2(p2,p3), pad} -- single random line-touch per edge.
// p = exp(lrelu(a_src[s]+a_dst[d])) (unnormalized; softmax shift-invariance
// makes max-subtraction unnecessary: logits are bounded, fp16-safe).
__global__ void scatter(const int* __restrict__ ei, const int* __restrict__ flag,
                        const int* __restrict__ off, int* __restrict__ cursor,
                        int4* __restrict__ recs,
                        const float* __restrict__ a_src, const float* __restrict__ a_dst,
                        int E, int n) {
    int i = blockIdx.x * 256 + threadIdx.x;
    if (i >= E + n) return;
    int f64 = *flag;
    int s, d;
    if (i < E) {
        if (f64) { s = ei[2 * (size_t)i]; d = ei[2 * ((size_t)E + i)]; }
        else     { s = ei[i];             d = ei[(size_t)E + i]; }
    } else {
        s = d = i - E;  // self loop
    }
    int pos = off[d] + atomicAdd(&cursor[d], 1);
    float4 as = ((const float4*)a_src)[s];
    float4 ad = ((const float4*)a_dst)[d];
    int4 rec;
    rec.x = s;
    rec.y = (int)pack_h2(__expf(lrelu(as.x + ad.x)), __expf(lrelu(as.y + ad.y)));
    rec.z = (int)pack_h2(__expf(lrelu(as.z + ad.z)), __expf(lrelu(as.w + ad.w)));
    rec.w = 0;
    recs[pos] = rec;
}

// ---------------------------------------------------------------------------
// Gather-accumulate (fp16 h) for one half-wave: lane L=lane&31 owns ch 4L..4L+3
// (8B per edge). Edges j = half, half+2, ...; unroll x4 -> 4 gathers in flight.
__device__ __forceinline__ void accum_half(const int* ssrc, const float* sal,
                                           const __half* __restrict__ h,
                                           int deg, int half, int L, int head,
                                           float4& acc) {
    float4 a0 = {0, 0, 0, 0}, a1 = {0, 0, 0, 0}, a2 = {0, 0, 0, 0}, a3 = {0, 0, 0, 0};
    int j = half;
    for (; j + 6 < deg; j += 8) {
        int s0 = ssrc[j], s1 = ssrc[j + 2], s2 = ssrc[j + 4], s3 = ssrc[j + 6];
        float w0 = sal[(j << 2) + head];
        float w1 = sal[((j + 2) << 2) + head];
        float w2 = sal[((j + 4) << 2) + head];
        float w3 = sal[((j + 6) << 2) + head];
        uint2 u0 = *(const uint2*)(h + ((size_t)s0 << 7) + (L << 2));
        uint2 u1 = *(const uint2*)(h + ((size_t)s1 << 7) + (L << 2));
        uint2 u2 = *(const uint2*)(h + ((size_t)s2 << 7) + (L << 2));
        uint2 u3 = *(const uint2*)(h + ((size_t)s3 << 7) + (L << 2));
        float2 f0a = unpack_h2(u0.x), f0b = unpack_h2(u0.y);
        float2 f1a = unpack_h2(u1.x), f1b = unpack_h2(u1.y);
        float2 f2a = unpack_h2(u2.x), f2b = unpack_h2(u2.y);
        float2 f3a = unpack_h2(u3.x), f3b = unpack_h2(u3.y);
        a0.x = fmaf(w0, f0a.x, a0.x); a0.y = fmaf(w0, f0a.y, a0.y);
        a0.z = fmaf(w0, f0b.x, a0.z); a0.w = fmaf(w0, f0b.y, a0.w);
        a1.x = fmaf(w1, f1a.x, a1.x); a1.y = fmaf(w1, f1a.y, a1.y);
        a1.z = fmaf(w1, f1b.x, a1.z); a1.w = fmaf(w1, f1b.y, a1.w);
        a2.x = fmaf(w2, f2a.x, a2.x); a2.y = fmaf(w2, f2a.y, a2.y);
        a2.z = fmaf(w2, f2b.x, a2.z); a2.w = fmaf(w2, f2b.y, a2.w);
        a3.x = fmaf(w3, f3a.x, a3.x); a3.y = fmaf(w3, f3a.y, a3.y);
        a3.z = fmaf(w3, f3b.x, a3.z); a3.w = fmaf(w3, f3b.y, a3.w);
    }
    for (; j < deg; j += 2) {
        int s0 = ssrc[j];
        float w0 = sal[(j << 2) + head];
        uint2 u0 = *(const uint2*)(h + ((size_t)s0 << 7) + (L << 2));
        float2 f0a = unpack_h2(u0.x), f0b = unpack_h2(u0.y);
        a0.x = fmaf(w0, f0a.x, a0.x); a0.y = fmaf(w0, f0a.y, a0.y);
        a0.z = fmaf(w0, f0b.x, a0.z); a0.w = fmaf(w0, f0b.y, a0.w);
    }
    acc.x += a0.x + a1.x + a2.x + a3.x;
    acc.y += a0.y + a1.y + a2.y + a3.y;
    acc.z += a0.z + a1.z + a2.z + a3.z;
    acc.w += a0.w + a1.w + a2.w + a3.w;
}

// One wave per destination node. Accumulates with RAW p; normalizes once in
// the epilogue (softmax denominator), so no reduction blocks the gather.
__global__ __launch_bounds__(256) void aggregate(const __half* __restrict__ h,
                                                 const int4* __restrict__ recs,
                                                 const int* __restrict__ off,
                                                 const float* __restrict__ bias,
                                                 __half* __restrict__ agg, int n) {
    __shared__ int sh_src[4][64];
    __shared__ float sh_al[4][256];    // [edge][head]
    int wslot = threadIdx.x >> 6;
    int lane = threadIdx.x & 63;
    int wid = blockIdx.x * (blockDim.x >> 6) + wslot;
    int nw = gridDim.x * (blockDim.x >> 6);
    int L = lane & 31, half = lane >> 5, head = L >> 3;
    float4 b4 = ((const float4*)bias)[L];
    int* ssrc = sh_src[wslot];
    float* sal = sh_al[wslot];

    for (int node = wid; node < n; node += nw) {
        int start = off[node], end = off[node + 1];
        int deg = end - start;          // >= 1 (self loop)
        float4 acc = {0.f, 0.f, 0.f, 0.f};
        float4 psum = {0.f, 0.f, 0.f, 0.f};

        if (deg <= 64) {
            bool v = lane < deg;
            int idx = start + (v ? lane : 0);
            int4 rec = recs[idx];
            float2 pa = unpack_h2((unsigned)rec.y);
            float2 pb = unpack_h2((unsigned)rec.z);
            float4 p = {pa.x, pa.y, pb.x, pb.y};
            if (!v) p = make_float4(0.f, 0.f, 0.f, 0.f);
            psum = p;
            ssrc[lane] = rec.x;
            *(float4*)&sal[lane << 2] = p;
            asm volatile("s_waitcnt lgkmcnt(0)" ::: "memory");
            accum_half(ssrc, sal, h, deg, half, L, head, acc);
            asm volatile("" ::: "memory");
        } else {
            // chunked path (rare: mean degree ~17)
            for (int bb = 0; bb < deg; bb += 64) {
                int i = bb + lane;
                bool v = i < deg;
                int idx = start + (v ? i : 0);
                int4 rec = recs[idx];
                float2 pa = unpack_h2((unsigned)rec.y);
                float2 pb = unpack_h2((unsigned)rec.z);
                float4 p = {pa.x, pa.y, pb.x, pb.y};
                if (!v) p = make_float4(0.f, 0.f, 0.f, 0.f);
                psum.x += p.x; psum.y += p.y; psum.z += p.z; psum.w += p.w;
                ssrc[lane] = rec.x;
                *(float4*)&sal[lane << 2] = p;
                asm volatile("s_waitcnt lgkmcnt(0)" ::: "memory");
                int cl = deg - bb;
                if (cl > 64) cl = 64;
                accum_half(ssrc, sal, h, cl, half, L, head, acc);
                asm volatile("" ::: "memory");
            }
        }
        float s0 = wred_sum(psum.x), s1 = wred_sum(psum.y);
        float s2 = wred_sum(psum.z), s3 = wred_sum(psum.w);
        float sh = (head == 0) ? s0 : (head == 1) ? s1 : (head == 2) ? s2 : s3;
        float inv = 1.f / sh;
        acc.x += __shfl_xor(acc.x, 32);
        acc.y += __shfl_xor(acc.y, 32);
        acc.z += __shfl_xor(acc.z, 32);
        acc.w += __shfl_xor(acc.w, 32);
        if (lane < 32) {
            float4 res = {fmaf(acc.x, inv, b4.x), fmaf(acc.y, inv, b4.y),
                          fmaf(acc.z, inv, b4.z), fmaf(acc.w, inv, b4.w)};
            uint2 u;
            u.x = pack_h2(res.x, res.y);
            u.y = pack_h2(res.z, res.w);
            *(uint2*)(agg + ((size_t)node << 7) + (L << 2)) = u;
        }
    }
}

// ---------------------------------------------------------------------------
// out[n][32] = elu(agg[n][128] (fp16) @ W_lin^T + b_lin)
__global__ __launch_bounds__(256) void proj(const __half* __restrict__ agg,
                                            const float* __restrict__ W_lin,
                                            const float* __restrict__ b_lin,
                                            float* __restrict__ out, int n) {
    __shared__ float xs[64][132];
    __shared__ float wt[128][36];   // wt[k][o]
    int tid = threadIdx.x;
    const float4* w4 = (const float4*)W_lin;
#pragma unroll
    for (int i = 0; i < 4; ++i) {
        int f4 = (i << 8) + tid;          // 0..1023
        int o = f4 >> 5, kk = (f4 & 31) << 2;
        float4 w = w4[f4];
        wt[kk][o] = w.x;
        wt[kk + 1][o] = w.y;
        wt[kk + 2][o] = w.z;
        wt[kk + 3][o] = w.w;
    }
    int rowbase = blockIdx.x << 6;
    const uint4* a4 = (const uint4*)agg;   // 8 halves per uint4; 16 per row
#pragma unroll
    for (int i = 0; i < 4; ++i) {
        int f8 = (i << 8) + tid;          // 0..1023
        int r = f8 >> 4, cc = (f8 & 15) << 3;
        int row = rowbase + r;
        if (row >= n) row = n - 1;
        uint4 u = a4[((size_t)row << 4) + (cc >> 3)];
        float2 f0 = unpack_h2(u.x), f1 = unpack_h2(u.y);
        float2 f2 = unpack_h2(u.z), f3 = unpack_h2(u.w);
        float* xp = &xs[r][cc];
        xp[0] = f0.x; xp[1] = f0.y; xp[2] = f1.x; xp[3] = f1.y;
        xp[4] = f2.x; xp[5] = f2.y; xp[6] = f3.x; xp[7] = f3.y;
    }
    __syncthreads();
    int r = tid >> 2, cg = tid & 3, c0 = cg << 3;
    float acc[8];
#pragma unroll
    for (int j = 0; j < 8; ++j) acc[j] = 0.f;
    for (int k = 0; k < 128; k += 4) {
        float4 xv = *(const float4*)&xs[r][k];
        float xk[4] = {xv.x, xv.y, xv.z, xv.w};
#pragma unroll
        for (int kk = 0; kk < 4; ++kk) {
            float4 wa = *(const float4*)&wt[k + kk][c0];
            float4 wb = *(const float4*)&wt[k + kk][c0 + 4];
            acc[0] = fmaf(xk[kk], wa.x, acc[0]);
            acc[1] = fmaf(xk[kk], wa.y, acc[1]);
            acc[2] = fmaf(xk[kk], wa.z, acc[2]);
            acc[3] = fmaf(xk[kk], wa.w, acc[3]);
            acc[4] = fmaf(xk[kk], wb.x, acc[4]);
            acc[5] = fmaf(xk[kk], wb.y, acc[5]);
            acc[6] = fmaf(xk[kk], wb.z, acc[6]);
            acc[7] = fmaf(xk[kk], wb.w, acc[7]);
        }
    }
    int row = rowbase + r;
    if (row < n) {
        float res[8];
#pragma unroll
        for (int j = 0; j < 8; ++j) {
            float v = acc[j] + b_lin[c0 + j];
            res[j] = v > 0.f ? v : (__expf(v) - 1.f);
        }
        float4* op = (float4*)(out + (size_t)row * 32 + c0);
        op[0] = make_float4(res[0], res[1], res[2], res[3]);
        op[1] = make_float4(res[4], res[5], res[6], res[7]);
    }
}

// ---------------------------------------------------------------------------
extern "C" void kernel_launch(void* const* d_in, const int* in_sizes, int n_in,
                              void* d_out, int out_size, void* d_ws, size_t ws_size,
                              hipStream_t stream) {
    const float* x = (const float*)d_in[0];
    const int* ei = (const int*)d_in[1];
    const float* W = (const float*)d_in[2];
    const float* att_src = (const float*)d_in[3];
    const float* att_dst = (const float*)d_in[4];
    const float* bias_conv = (const float*)d_in[5];
    const float* W_lin = (const float*)d_in[6];
    const float* b_lin = (const float*)d_in[7];
    int n = in_sizes[0] / IN_CH;
    int E = in_sizes[1] / 2;

    char* ws = (char*)d_ws;
    size_t o = 0;
    auto alloc = [&](size_t bytes) { char* p = ws + o; o = align256(o + bytes); return p; };
    __half* h      = (__half*)alloc((size_t)n * HC * 2);
    __half* agg    = (__half*)alloc((size_t)n * HC * 2);
    float* wtg     = (float*)alloc(128 * 128 * 4);
    float* a_src   = (float*)alloc((size_t)n * NHEADS * 4);
    float* a_dst   = (float*)alloc((size_t)n * NHEADS * 4);
    int* deg       = (int*)alloc((size_t)n * 4);
    int* cursor    = (int*)alloc((size_t)n * 4);
    int* off       = (int*)alloc(((size_t)n + 1) * 4);
    int* chunkTot  = (int*)alloc(256 * 4);
    int* chunkBase = (int*)alloc(256 * 4);
    int* flag      = (int*)alloc(256);
    int4* recs     = (int4*)alloc((size_t)(E + n + 64) * 16);

    hipMemsetAsync(deg, 0, (size_t)n * 4, stream);
    hipMemsetAsync(cursor, 0, (size_t)n * 4, stream);

    detect_dtype<<<1, 256, 0, stream>>>(ei, flag);
    wtrans<<<64, 256, 0, stream>>>(W, wtg);
    gemm_h<<<(n + 63) / 64, 256, 0, stream>>>(x, wtg, att_src, att_dst, h, a_src, a_dst, n);
    hist<<<(E + 255) / 256, 256, 0, stream>>>(ei, flag, deg, E);
    int nchunks = (n + 2047) / 2048;
    scan1<<<nchunks, 256, 0, stream>>>(deg, off, chunkTot, n);
    scan2<<<1, 64, 0, stream>>>(chunkTot, chunkBase, nchunks);
    finalize<<<(n + 1 + 255) / 256, 256, 0, stream>>>(off, chunkBase, n, E);
    scatter<<<(E + n + 255) / 256, 256, 0, stream>>>(ei, flag, off, cursor, recs,
                                                     a_src, a_dst, E, n);
    aggregate<<<2048, 256, 0, stream>>>(h, recs, off, bias_conv, agg, n);
    proj<<<(n + 63) / 64, 256, 0, stream>>>(agg, W_lin, b_lin, (float*)d_out, n);
}

// Round 5
// 397.846 us; speedup vs baseline: 1.2646x; 1.0652x over previous
//
#include <hip/hip_runtime.h>
#include <hip/hip_fp16.h>
#include <cstdint>
#include <cstddef>

#define NHEADS 4
#define OUT_C 32
#define HC 128          // NHEADS*OUT_C
#define IN_CH 128
#define NEG_SLOPE 0.2f
#define LDSPAD 136      // halves per LDS row (128 + 8 pad -> 2-way-max bank aliasing)

typedef _Float16 half8 __attribute__((ext_vector_type(8)));
typedef float floatx4 __attribute__((ext_vector_type(4)));

static inline size_t align256(size_t v) { return (v + 255) & ~(size_t)255; }

__device__ __forceinline__ float lrelu(float v) { return v > 0.f ? v : NEG_SLOPE * v; }

__device__ __forceinline__ float wred_sum(float v) {
    v += __shfl_xor(v, 1);
    v += __shfl_xor(v, 2);
    v += __shfl_xor(v, 4);
    v += __shfl_xor(v, 8);
    v += __shfl_xor(v, 16);
    v += __shfl_xor(v, 32);
    return v;
}

__device__ __forceinline__ unsigned int pack_h2(float a, float b) {
    __half2 h = __floats2half2_rn(a, b);
    return *reinterpret_cast<unsigned int*>(&h);
}
__device__ __forceinline__ float2 unpack_h2(unsigned int u) {
    __half2 h = *reinterpret_cast<__half2*>(&u);
    return __half22float2(h);
}

// ---------------------------------------------------------------------------
// Detect whether edge_index is int64 (odd 4B words all zero for values<2^31)
// or int32. Writes flag=1 for int64, 0 for int32.
__global__ void detect_dtype(const int* __restrict__ ei, int* __restrict__ flag) {
    __shared__ int red[256];
    int t = threadIdx.x;
    int acc = 0;
    for (int i = t; i < 1024; i += 256) acc |= ei[2 * i + 1];
    red[t] = acc;
    __syncthreads();
    for (int s = 128; s > 0; s >>= 1) {
        if (t < s) red[t] |= red[t + s];
        __syncthreads();
    }
    if (t == 0) *flag = (red[0] == 0) ? 1 : 0;
}

// ---------------------------------------------------------------------------
// W [128 out][128 in] fp32 -> fp16 copy (layout kept: [n][k], exactly the
// MFMA B-operand layout)
__global__ void whconv(const float* __restrict__ W, _Float16* __restrict__ wh) {
    int idx = blockIdx.x * 256 + threadIdx.x;
    if (idx < 128 * 128) wh[idx] = (_Float16)W[idx];
}

// ---------------------------------------------------------------------------
// h[n][128] (fp16) = x[n][128] @ W^T via MFMA 16x16x32 f16 (fp32 accum).
// 128x128 tile/block, 4 waves: wave w covers rows w*32..w*32+31, all 128 cols.
// Fused epilogue: h-tile staged to LDS for coalesced stores + attention
// logits a_src/a_dst.
__global__ __launch_bounds__(256) void gemm_h(const float* __restrict__ x,
                                              const _Float16* __restrict__ wh,
                                              const float* __restrict__ att_src,
                                              const float* __restrict__ att_dst,
                                              __half* __restrict__ h,
                                              float* __restrict__ a_src,
                                              float* __restrict__ a_dst, int n) {
    __shared__ __align__(16) _Float16 Ws[128 * LDSPAD];
    __shared__ __align__(16) _Float16 Xs[128 * LDSPAD];   // reused as h-tile
    int tid = threadIdx.x;
    int rowbase = blockIdx.x << 7;

    // stage W: 128x128 halves (2048 uint4)
    const uint4* w4 = (const uint4*)wh;
#pragma unroll
    for (int i = 0; i < 8; ++i) {
        int u = (i << 8) + tid;
        int r = u >> 4, g = u & 15;
        uint4 v = w4[u];
        *(uint4*)&Ws[r * LDSPAD + (g << 3)] = v;
    }
    // stage x tile: fp32 -> fp16 (4096 float4)
    const float4* x4 = (const float4*)x;
#pragma unroll
    for (int i = 0; i < 16; ++i) {
        int u = (i << 8) + tid;
        int r = u >> 5, c4 = u & 31;
        int row = rowbase + r;
        if (row >= n) row = n - 1;
        float4 v = x4[((size_t)row << 5) + c4];
        uint2 uu;
        uu.x = pack_h2(v.x, v.y);
        uu.y = pack_h2(v.z, v.w);
        *(uint2*)&Xs[r * LDSPAD + (c4 << 2)] = uu;
    }
    __syncthreads();

    int lane = tid & 63, w = tid >> 6;
    int quad = lane >> 4, Lm = lane & 15;
    floatx4 acc[2][8];
#pragma unroll
    for (int rt = 0; rt < 2; ++rt)
#pragma unroll
        for (int c = 0; c < 8; ++c) acc[rt][c] = (floatx4){0.f, 0.f, 0.f, 0.f};

#pragma unroll
    for (int kc = 0; kc < 128; kc += 32) {
        int ko = kc + (quad << 3);
        half8 a0 = *(const half8*)&Xs[((w << 5) + Lm) * LDSPAD + ko];
        half8 a1 = *(const half8*)&Xs[((w << 5) + 16 + Lm) * LDSPAD + ko];
#pragma unroll
        for (int c = 0; c < 8; ++c) {
            half8 b = *(const half8*)&Ws[((c << 4) + Lm) * LDSPAD + ko];
            acc[0][c] = __builtin_amdgcn_mfma_f32_16x16x32_f16(a0, b, acc[0][c], 0, 0, 0);
            acc[1][c] = __builtin_amdgcn_mfma_f32_16x16x32_f16(a1, b, acc[1][c], 0, 0, 0);
        }
    }
    __syncthreads();
    // D layout: row = quad*4 + i, col = lane&15 (per 16x16 tile) -> stage to Xs
#pragma unroll
    for (int rt = 0; rt < 2; ++rt)
#pragma unroll
        for (int c = 0; c < 8; ++c)
#pragma unroll
            for (int i = 0; i < 4; ++i) {
                int rl = (w << 5) + (rt << 4) + (quad << 2) + i;
                int cl = (c << 4) + Lm;
                Xs[rl * LDSPAD + cl] = (_Float16)acc[rt][c][i];
            }
    __syncthreads();
    // coalesced global store of h tile
#pragma unroll
    for (int i = 0; i < 8; ++i) {
        int u = (i << 8) + tid;
        int r = u >> 4, g = u & 15;
        int row = rowbase + r;
        if (row < n) {
            uint4 v = *(uint4*)&Xs[r * LDSPAD + (g << 3)];
            *(uint4*)(h + ((size_t)row << 7) + (g << 3)) = v;
        }
    }
    // attention logits: thread covers row r=tid>>1, cols seg*64..+63 (heads 2seg, 2seg+1)
    int r = tid >> 1, seg = tid & 1;
    int row = rowbase + r;
    const _Float16* hp = &Xs[r * LDSPAD + (seg << 6)];
    float sa = 0.f, da = 0.f, sb = 0.f, db = 0.f;
#pragma unroll
    for (int g8 = 0; g8 < 8; ++g8) {
        half8 v = *(const half8*)&hp[g8 << 3];
        int co = (seg << 6) + (g8 << 3);
        float4 A1 = *(const float4*)&att_src[co];
        float4 A2 = *(const float4*)&att_src[co + 4];
        float4 D1 = *(const float4*)&att_dst[co];
        float4 D2 = *(const float4*)&att_dst[co + 4];
        float f0 = (float)v[0], f1 = (float)v[1], f2 = (float)v[2], f3 = (float)v[3];
        float f4 = (float)v[4], f5 = (float)v[5], f6 = (float)v[6], f7 = (float)v[7];
        float ts = f0 * A1.x + f1 * A1.y + f2 * A1.z + f3 * A1.w
                 + f4 * A2.x + f5 * A2.y + f6 * A2.z + f7 * A2.w;
        float td = f0 * D1.x + f1 * D1.y + f2 * D1.z + f3 * D1.w
                 + f4 * D2.x + f5 * D2.y + f6 * D2.z + f7 * D2.w;
        if (g8 < 4) { sa += ts; da += td; } else { sb += ts; db += td; }
    }
    if (row < n) {
        int base = (row << 2) + (seg << 1);
        a_src[base] = sa;
        a_src[base + 1] = sb;
        a_dst[base] = da;
        a_dst[base + 1] = db;
    }
}

// ---------------------------------------------------------------------------
// histogram of dst (edges only; self-loops added as +1 in scan)
__global__ void hist(const int* __restrict__ ei, const int* __restrict__ flag,
                     int* __restrict__ deg, int E) {
    int i = blockIdx.x * 256 + threadIdx.x;
    if (i >= E) return;
    int f64 = *flag;
    int d = f64 ? ei[2 * ((size_t)E + i)] : ei[(size_t)E + i];
    atomicAdd(&deg[d], 1);
}

// chunked exclusive scan, chunk=2048 (256 thr x 8)
__global__ void scan1(const int* __restrict__ deg, int* __restrict__ off,
                      int* __restrict__ tot, int n) {
    __shared__ int ts[256];
    int t = threadIdx.x;
    int i0 = (blockIdx.x << 11) + (t << 3);
    int pref[8];
    int sum = 0;
#pragma unroll
    for (int j = 0; j < 8; ++j) {
        int i = i0 + j;
        int v = (i < n) ? (deg[i] + 1) : 0;  // +1 = self loop
        pref[j] = sum;
        sum += v;
    }
    ts[t] = sum;
    __syncthreads();
    int run = sum;
    for (int d = 1; d < 256; d <<= 1) {
        int o = (t >= d) ? ts[t - d] : 0;
        __syncthreads();
        run += o;
        ts[t] = run;
        __syncthreads();
    }
    int excl = run - sum;
#pragma unroll
    for (int j = 0; j < 8; ++j) {
        int i = i0 + j;
        if (i < n) off[i] = excl + pref[j];
    }
    if (t == 255) tot[blockIdx.x] = run;
}

__global__ void scan2(const int* __restrict__ tot, int* __restrict__ cbase, int nc) {
    int lane = threadIdx.x;  // 64 threads, 1 wave
    int carry = 0;
    for (int b = 0; b < nc; b += 64) {
        int i = b + lane;
        int v = (i < nc) ? tot[i] : 0;
        int orig = v;
        for (int d = 1; d < 64; d <<= 1) {
            int u = __shfl_up(v, d);
            if (lane >= d) v += u;
        }
        if (i < nc) cbase[i] = carry + v - orig;
        carry += __shfl(v, 63);
    }
}

__global__ void finalize(int* __restrict__ off, const int* __restrict__ cbase, int n, int E) {
    int i = blockIdx.x * 256 + threadIdx.x;
    if (i < n) off[i] += cbase[i >> 11];
    else if (i == n) off[n] = E + n;
}

// ---------------------------------------------------------------------------
// Counting-sort scatter + fused alpha computation. One 16B record per edge:
// {src, half2(p0,p1), half2(p2,p3), pad}. p = exp(lrelu(a_src[s]+a_dst[d]))
// unnormalized (softmax shift-invariance; logits bounded, fp16-safe).
__global__ void scatter(const int* __restrict__ ei, const int* __restrict__ flag,
                        const int* __restrict__ off, int* __restrict__ cursor,
                        int4* __restrict__ recs,
                        const float* __restrict__ a_src, const float* __restrict__ a_dst,
                        int E, int n) {
    int i = blockIdx.x * 256 + threadIdx.x;
    if (i >= E + n) return;
    int f64 = *flag;
    int s, d;
    if (i < E) {
        if (f64) { s = ei[2 * (size_t)i]; d = ei[2 * ((size_t)E + i)]; }
        else     { s = ei[i];             d = ei[(size_t)E + i]; }
    } else {
        s = d = i - E;  // self loop
    }
    int pos = off[d] + atomicAdd(&cursor[d], 1);
    float4 as = ((const float4*)a_src)[s];
    float4 ad = ((const float4*)a_dst)[d];
    int4 rec;
    rec.x = s;
    rec.y = (int)pack_h2(__expf(lrelu(as.x + ad.x)), __expf(lrelu(as.y + ad.y)));
    rec.z = (int)pack_h2(__expf(lrelu(as.z + ad.z)), __expf(lrelu(as.w + ad.w)));
    rec.w = 0;
    recs[pos] = rec;
}

// ---------------------------------------------------------------------------
// One wave per destination node, full wave per edge: lane L owns channels
// 2L..2L+1 (one dword gather per lane per edge = one 256B h row per instr).
// Unroll x8 -> 8 independent gathers in flight. Normalization deferred to
// epilogue (alphas pre-exp'd, unnormalized).
__global__ __launch_bounds__(256) void aggregate(const __half* __restrict__ h,
                                                 const int4* __restrict__ recs,
                                                 const int* __restrict__ off,
                                                 const float* __restrict__ bias,
                                                 __half* __restrict__ agg, int n) {
    __shared__ __align__(16) int sh_src[4][64];
    __shared__ __align__(16) float sh_al[4][256];    // [edge][head]
    int wslot = threadIdx.x >> 6;
    int lane = threadIdx.x & 63;
    int wid = blockIdx.x * 4 + wslot;
    int nw = gridDim.x * 4;
    int head = lane >> 4;          // channels 2L,2L+1 -> head = 2L>>5 = L>>4
    float2 b2 = ((const float2*)bias)[lane];
    int* ssrc = sh_src[wslot];
    float* sal = sh_al[wslot];
    const __half* hL = h + (lane << 1);

    for (int node = wid; node < n; node += nw) {
        int start = off[node], end = off[node + 1];
        int deg = end - start;          // >= 1 (self loop)
        float ax0 = 0.f, ay0 = 0.f, ax1 = 0.f, ay1 = 0.f;
        float ax2 = 0.f, ay2 = 0.f, ax3 = 0.f, ay3 = 0.f;
        float4 psum = {0.f, 0.f, 0.f, 0.f};

        if (deg <= 64) {
            bool v = lane < deg;
            int idx = start + (v ? lane : 0);
            int4 rec = recs[idx];
            float2 pa = unpack_h2((unsigned)rec.y);
            float2 pb = unpack_h2((unsigned)rec.z);
            float4 p = {pa.x, pa.y, pb.x, pb.y};
            if (!v) p = make_float4(0.f, 0.f, 0.f, 0.f);
            psum = p;
            ssrc[lane] = rec.x;
            *(float4*)&sal[lane << 2] = p;
            asm volatile("s_waitcnt lgkmcnt(0)" ::: "memory");
            int j = 0;
            for (; j + 7 < deg; j += 8) {
                int4 sA = *(const int4*)&ssrc[j];
                int4 sB = *(const int4*)&ssrc[j + 4];
                float w0 = sal[((j + 0) << 2) + head];
                float w1 = sal[((j + 1) << 2) + head];
                float w2 = sal[((j + 2) << 2) + head];
                float w3 = sal[((j + 3) << 2) + head];
                float w4 = sal[((j + 4) << 2) + head];
                float w5 = sal[((j + 5) << 2) + head];
                float w6 = sal[((j + 6) << 2) + head];
                float w7 = sal[((j + 7) << 2) + head];
                unsigned u0 = *(const unsigned*)(hL + ((size_t)sA.x << 7));
                unsigned u1 = *(const unsigned*)(hL + ((size_t)sA.y << 7));
                unsigned u2 = *(const unsigned*)(hL + ((size_t)sA.z << 7));
                unsigned u3 = *(const unsigned*)(hL + ((size_t)sA.w << 7));
                unsigned u4 = *(const unsigned*)(hL + ((size_t)sB.x << 7));
                unsigned u5 = *(const unsigned*)(hL + ((size_t)sB.y << 7));
                unsigned u6 = *(const unsigned*)(hL + ((size_t)sB.z << 7));
                unsigned u7 = *(const unsigned*)(hL + ((size_t)sB.w << 7));
                float2 f;
                f = unpack_h2(u0); ax0 = fmaf(w0, f.x, ax0); ay0 = fmaf(w0, f.y, ay0);
                f = unpack_h2(u1); ax1 = fmaf(w1, f.x, ax1); ay1 = fmaf(w1, f.y, ay1);
                f = unpack_h2(u2); ax2 = fmaf(w2, f.x, ax2); ay2 = fmaf(w2, f.y, ay2);
                f = unpack_h2(u3); ax3 = fmaf(w3, f.x, ax3); ay3 = fmaf(w3, f.y, ay3);
                f = unpack_h2(u4); ax0 = fmaf(w4, f.x, ax0); ay0 = fmaf(w4, f.y, ay0);
                f = unpack_h2(u5); ax1 = fmaf(w5, f.x, ax1); ay1 = fmaf(w5, f.y, ay1);
                f = unpack_h2(u6); ax2 = fmaf(w6, f.x, ax2); ay2 = fmaf(w6, f.y, ay2);
                f = unpack_h2(u7); ax3 = fmaf(w7, f.x, ax3); ay3 = fmaf(w7, f.y, ay3);
            }
            for (; j < deg; ++j) {
                int s = ssrc[j];
                float wv = sal[(j << 2) + head];
                unsigned u = *(const unsigned*)(hL + ((size_t)s << 7));
                float2 f = unpack_h2(u);
                ax0 = fmaf(wv, f.x, ax0); ay0 = fmaf(wv, f.y, ay0);
            }
        } else {
            // chunked path (rare)
            for (int bb = 0; bb < deg; bb += 64) {
                int i = bb + lane;
                bool v = i < deg;
                int idx = start + (v ? i : 0);
                int4 rec = recs[idx];
                float2 pa = unpack_h2((unsigned)rec.y);
                float2 pb = unpack_h2((unsigned)rec.z);
                float4 p = {pa.x, pa.y, pb.x, pb.y};
                if (!v) p = make_float4(0.f, 0.f, 0.f, 0.f);
                psum.x += p.x; psum.y += p.y; psum.z += p.z; psum.w += p.w;
                ssrc[lane] = rec.x;
                *(float4*)&sal[lane << 2] = p;
                asm volatile("s_waitcnt lgkmcnt(0)" ::: "memory");
                int cl = deg - bb;
                if (cl > 64) cl = 64;
                int j = 0;
                for (; j + 7 < cl; j += 8) {
                    int4 sA = *(const int4*)&ssrc[j];
                    int4 sB = *(const int4*)&ssrc[j + 4];
                    float w0 = sal[((j + 0) << 2) + head];
                    float w1 = sal[((j + 1) << 2) + head];
                    float w2 = sal[((j + 2) << 2) + head];
                    float w3 = sal[((j + 3) << 2) + head];
                    float w4 = sal[((j + 4) << 2) + head];
                    float w5 = sal[((j + 5) << 2) + head];
                    float w6 = sal[((j + 6) << 2) + head];
                    float w7 = sal[((j + 7) << 2) + head];
                    unsigned u0 = *(const unsigned*)(hL + ((size_t)sA.x << 7));
                    unsigned u1 = *(const unsigned*)(hL + ((size_t)sA.y << 7));
                    unsigned u2 = *(const unsigned*)(hL + ((size_t)sA.z << 7));
                    unsigned u3 = *(const unsigned*)(hL + ((size_t)sA.w << 7));
                    unsigned u4 = *(const unsigned*)(hL + ((size_t)sB.x << 7));
                    unsigned u5 = *(const unsigned*)(hL + ((size_t)sB.y << 7));
                    unsigned u6 = *(const unsigned*)(hL + ((size_t)sB.z << 7));
                    unsigned u7 = *(const unsigned*)(hL + ((size_t)sB.w << 7));
                    float2 f;
                    f = unpack_h2(u0); ax0 = fmaf(w0, f.x, ax0); ay0 = fmaf(w0, f.y, ay0);
                    f = unpack_h2(u1); ax1 = fmaf(w1, f.x, ax1); ay1 = fmaf(w1, f.y, ay1);
                    f = unpack_h2(u2); ax2 = fmaf(w2, f.x, ax2); ay2 = fmaf(w2, f.y, ay2);
                    f = unpack_h2(u3); ax3 = fmaf(w3, f.x, ax3); ay3 = fmaf(w3, f.y, ay3);
                    f = unpack_h2(u4); ax0 = fmaf(w4, f.x, ax0); ay0 = fmaf(w4, f.y, ay0);
                    f = unpack_h2(u5); ax1 = fmaf(w5, f.x, ax1); ay1 = fmaf(w5, f.y, ay1);
                    f = unpack_h2(u6); ax2 = fmaf(w6, f.x, ax2); ay2 = fmaf(w6, f.y, ay2);
                    f = unpack_h2(u7); ax3 = fmaf(w7, f.x, ax3); ay3 = fmaf(w7, f.y, ay3);
                }
                for (; j < cl; ++j) {
                    int s = ssrc[j];
                    float wv = sal[(j << 2) + head];
                    unsigned u = *(const unsigned*)(hL + ((size_t)s << 7));
                    float2 f = unpack_h2(u);
                    ax0 = fmaf(wv, f.x, ax0); ay0 = fmaf(wv, f.y, ay0);
                }
                asm volatile("" ::: "memory");
            }
        }
        float s0 = wred_sum(psum.x), s1 = wred_sum(psum.y);
        float s2 = wred_sum(psum.z), s3 = wred_sum(psum.w);
        float sh = (head == 0) ? s0 : (head == 1) ? s1 : (head == 2) ? s2 : s3;
        float inv = 1.f / sh;
        float rx = (ax0 + ax1) + (ax2 + ax3);
        float ry = (ay0 + ay1) + (ay2 + ay3);
        float ox = fmaf(rx, inv, b2.x);
        float oy = fmaf(ry, inv, b2.y);
        *(unsigned*)(agg + ((size_t)node << 7) + (lane << 1)) = pack_h2(ox, oy);
    }
}

// ---------------------------------------------------------------------------
// out[n][32] = elu(agg[n][128] (fp16) @ W_lin^T + b_lin)
__global__ __launch_bounds__(256) void proj(const __half* __restrict__ agg,
                                            const float* __restrict__ W_lin,
                                            const float* __restrict__ b_lin,
                                            float* __restrict__ out, int n) {
    __shared__ float xs[64][132];
    __shared__ float wt[128][36];   // wt[k][o]
    int tid = threadIdx.x;
    const float4* w4 = (const float4*)W_lin;
#pragma unroll
    for (int i = 0; i < 4; ++i) {
        int f4 = (i << 8) + tid;          // 0..1023
        int o = f4 >> 5, kk = (f4 & 31) << 2;
        float4 w = w4[f4];
        wt[kk][o] = w.x;
        wt[kk + 1][o] = w.y;
        wt[kk + 2][o] = w.z;
        wt[kk + 3][o] = w.w;
    }
    int rowbase = blockIdx.x << 6;
    const uint4* a4 = (const uint4*)agg;   // 8 halves per uint4; 16 per row
#pragma unroll
    for (int i = 0; i < 4; ++i) {
        int f8 = (i << 8) + tid;          // 0..1023
        int r = f8 >> 4, cc = (f8 & 15) << 3;
        int row = rowbase + r;
        if (row >= n) row = n - 1;
        uint4 u = a4[((size_t)row << 4) + (cc >> 3)];
        float2 f0 = unpack_h2(u.x), f1 = unpack_h2(u.y);
        float2 f2 = unpack_h2(u.z), f3 = unpack_h2(u.w);
        float* xp = &xs[r][cc];
        xp[0] = f0.x; xp[1] = f0.y; xp[2] = f1.x; xp[3] = f1.y;
        xp[4] = f2.x; xp[5] = f2.y; xp[6] = f3.x; xp[7] = f3.y;
    }
    __syncthreads();
    int r = tid >> 2, cg = tid & 3, c0 = cg << 3;
    float acc[8];
#pragma unroll
    for (int j = 0; j < 8; ++j) acc[j] = 0.f;
    for (int k = 0; k < 128; k += 4) {
        float4 xv = *(const float4*)&xs[r][k];
        float xk[4] = {xv.x, xv.y, xv.z, xv.w};
#pragma unroll
        for (int kk = 0; kk < 4; ++kk) {
            float4 wa = *(const float4*)&wt[k + kk][c0];
            float4 wb = *(const float4*)&wt[k + kk][c0 + 4];
            acc[0] = fmaf(xk[kk], wa.x, acc[0]);
            acc[1] = fmaf(xk[kk], wa.y, acc[1]);
            acc[2] = fmaf(xk[kk], wa.z, acc[2]);
            acc[3] = fmaf(xk[kk], wa.w, acc[3]);
            acc[4] = fmaf(xk[kk], wb.x, acc[4]);
            acc[5] = fmaf(xk[kk], wb.y, acc[5]);
            acc[6] = fmaf(xk[kk], wb.z, acc[6]);
            acc[7] = fmaf(xk[kk], wb.w, acc[7]);
        }
    }
    int row = rowbase + r;
    if (row < n) {
        float res[8];
#pragma unroll
        for (int j = 0; j < 8; ++j) {
            float v = acc[j] + b_lin[c0 + j];
            res[j] = v > 0.f ? v : (__expf(v) - 1.f);
        }
        float4* op = (float4*)(out + (size_t)row * 32 + c0);
        op[0] = make_float4(res[0], res[1], res[2], res[3]);
        op[1] = make_float4(res[4], res[5], res[6], res[7]);
    }
}

// ---------------------------------------------------------------------------
extern "C" void kernel_launch(void* const* d_in, const int* in_sizes, int n_in,
                              void* d_out, int out_size, void* d_ws, size_t ws_size,
                              hipStream_t stream) {
    const float* x = (const float*)d_in[0];
    const int* ei = (const int*)d_in[1];
    const float* W = (const float*)d_in[2];
    const float* att_src = (const float*)d_in[3];
    const float* att_dst = (const float*)d_in[4];
    const float* bias_conv = (const float*)d_in[5];
    const float* W_lin = (const float*)d_in[6];
    const float* b_lin = (const float*)d_in[7];
    int n = in_sizes[0] / IN_CH;
    int E = in_sizes[1] / 2;

    char* ws = (char*)d_ws;
    size_t o = 0;
    auto alloc = [&](size_t bytes) { char* p = ws + o; o = align256(o + bytes); return p; };
    __half* h      = (__half*)alloc((size_t)n * HC * 2);
    __half* agg    = (__half*)alloc((size_t)n * HC * 2);
    _Float16* wh   = (_Float16*)alloc(128 * 128 * 2);
    float* a_src   = (float*)alloc((size_t)n * NHEADS * 4);
    float* a_dst   = (float*)alloc((size_t)n * NHEADS * 4);
    int* deg       = (int*)alloc((size_t)n * 4);
    int* cursor    = (int*)alloc((size_t)n * 4);
    int* off       = (int*)alloc(((size_t)n + 1) * 4);
    int* chunkTot  = (int*)alloc(256 * 4);
    int* chunkBase = (int*)alloc(256 * 4);
    int* flag      = (int*)alloc(256);
    int4* recs     = (int4*)alloc((size_t)(E + n + 64) * 16);

    hipMemsetAsync(deg, 0, (size_t)n * 4, stream);
    hipMemsetAsync(cursor, 0, (size_t)n * 4, stream);

    detect_dtype<<<1, 256, 0, stream>>>(ei, flag);
    whconv<<<64, 256, 0, stream>>>(W, wh);
    gemm_h<<<(n + 127) / 128, 256, 0, stream>>>(x, wh, att_src, att_dst, h, a_src, a_dst, n);
    hist<<<(E + 255) / 256, 256, 0, stream>>>(ei, flag, deg, E);
    int nchunks = (n + 2047) / 2048;
    scan1<<<nchunks, 256, 0, stream>>>(deg, off, chunkTot, n);
    scan2<<<1, 64, 0, stream>>>(chunkTot, chunkBase, nchunks);
    finalize<<<(n + 1 + 255) / 256, 256, 0, stream>>>(off, chunkBase, n, E);
    scatter<<<(E + n + 255) / 256, 256, 0, stream>>>(ei, flag, off, cursor, recs,
                                                     a_src, a_dst, E, n);
    aggregate<<<2048, 256, 0, stream>>>(h, recs, off, bias_conv, agg, n);
    proj<<<(n + 63) / 64, 256, 0, stream>>>(agg, W_lin, b_lin, (float*)d_out, n);
}

// Round 6
// 396.735 us; speedup vs baseline: 1.2682x; 1.0028x over previous
//
#include <hip/hip_runtime.h>
#include <hip/hip_fp16.h>
#include <cstdint>
#include <cstddef>

#define NHEADS 4
#define OUT_C 32
#define HC 128          // NHEADS*OUT_C
#define IN_CH 128
#define NEG_SLOPE 0.2f
#define LDSPAD 136      // halves per LDS row (128 + 8 pad)

typedef _Float16 half8 __attribute__((ext_vector_type(8)));
typedef float floatx4 __attribute__((ext_vector_type(4)));

static inline size_t align256(size_t v) { return (v + 255) & ~(size_t)255; }

__device__ __forceinline__ float lrelu(float v) { return v > 0.f ? v : NEG_SLOPE * v; }

__device__ __forceinline__ float wred_sum(float v) {
    v += __shfl_xor(v, 1);
    v += __shfl_xor(v, 2);
    v += __shfl_xor(v, 4);
    v += __shfl_xor(v, 8);
    v += __shfl_xor(v, 16);
    v += __shfl_xor(v, 32);
    return v;
}
__device__ __forceinline__ int wred_isum(int v) {
    v += __shfl_xor(v, 1);
    v += __shfl_xor(v, 2);
    v += __shfl_xor(v, 4);
    v += __shfl_xor(v, 8);
    v += __shfl_xor(v, 16);
    v += __shfl_xor(v, 32);
    return v;
}

__device__ __forceinline__ unsigned int pack_h2(float a, float b) {
    __half2 h = __floats2half2_rn(a, b);
    return *reinterpret_cast<unsigned int*>(&h);
}
__device__ __forceinline__ float2 unpack_h2(unsigned int u) {
    __half2 h = *reinterpret_cast<__half2*>(&u);
    return __half22float2(h);
}

// ---------------------------------------------------------------------------
// Fused: blocks 0..63 convert W fp32->fp16; block 64 detects edge dtype
// (int64 <=> odd 4B words of first 1024 entries all zero).
__global__ void dw(const float* __restrict__ W, _Float16* __restrict__ wh,
                   const int* __restrict__ ei, int* __restrict__ flag) {
    if (blockIdx.x < 64) {
        int idx = blockIdx.x * 256 + threadIdx.x;
        wh[idx] = (_Float16)W[idx];
        return;
    }
    __shared__ int red[256];
    int t = threadIdx.x;
    int acc = 0;
    for (int i = t; i < 1024; i += 256) acc |= ei[2 * i + 1];
    red[t] = acc;
    __syncthreads();
    for (int s = 128; s > 0; s >>= 1) {
        if (t < s) red[t] |= red[t + s];
        __syncthreads();
    }
    if (t == 0) *flag = (red[0] == 0) ? 1 : 0;
}

// ---------------------------------------------------------------------------
// h[n][128] (fp16) = x[n][128] @ W^T via MFMA 16x16x32 f16 (fp32 accum).
// 128x128 tile/block, 4 waves. Fused epilogue: coalesced h store + attention
// logits a_src/a_dst.
__global__ __launch_bounds__(256) void gemm_h(const float* __restrict__ x,
                                              const _Float16* __restrict__ wh,
                                              const float* __restrict__ att_src,
                                              const float* __restrict__ att_dst,
                                              __half* __restrict__ h,
                                              float* __restrict__ a_src,
                                              float* __restrict__ a_dst, int n) {
    __shared__ __align__(16) _Float16 Ws[128 * LDSPAD];
    __shared__ __align__(16) _Float16 Xs[128 * LDSPAD];   // reused as h-tile
    int tid = threadIdx.x;
    int rowbase = blockIdx.x << 7;

    const uint4* w4 = (const uint4*)wh;
#pragma unroll
    for (int i = 0; i < 8; ++i) {
        int u = (i << 8) + tid;
        int r = u >> 4, g = u & 15;
        uint4 v = w4[u];
        *(uint4*)&Ws[r * LDSPAD + (g << 3)] = v;
    }
    const float4* x4 = (const float4*)x;
#pragma unroll
    for (int i = 0; i < 16; ++i) {
        int u = (i << 8) + tid;
        int r = u >> 5, c4 = u & 31;
        int row = rowbase + r;
        if (row >= n) row = n - 1;
        float4 v = x4[((size_t)row << 5) + c4];
        uint2 uu;
        uu.x = pack_h2(v.x, v.y);
        uu.y = pack_h2(v.z, v.w);
        *(uint2*)&Xs[r * LDSPAD + (c4 << 2)] = uu;
    }
    __syncthreads();

    int lane = tid & 63, w = tid >> 6;
    int quad = lane >> 4, Lm = lane & 15;
    floatx4 acc[2][8];
#pragma unroll
    for (int rt = 0; rt < 2; ++rt)
#pragma unroll
        for (int c = 0; c < 8; ++c) acc[rt][c] = (floatx4){0.f, 0.f, 0.f, 0.f};

#pragma unroll
    for (int kc = 0; kc < 128; kc += 32) {
        int ko = kc + (quad << 3);
        half8 a0 = *(const half8*)&Xs[((w << 5) + Lm) * LDSPAD + ko];
        half8 a1 = *(const half8*)&Xs[((w << 5) + 16 + Lm) * LDSPAD + ko];
#pragma unroll
        for (int c = 0; c < 8; ++c) {
            half8 b = *(const half8*)&Ws[((c << 4) + Lm) * LDSPAD + ko];
            acc[0][c] = __builtin_amdgcn_mfma_f32_16x16x32_f16(a0, b, acc[0][c], 0, 0, 0);
            acc[1][c] = __builtin_amdgcn_mfma_f32_16x16x32_f16(a1, b, acc[1][c], 0, 0, 0);
        }
    }
    __syncthreads();
#pragma unroll
    for (int rt = 0; rt < 2; ++rt)
#pragma unroll
        for (int c = 0; c < 8; ++c)
#pragma unroll
            for (int i = 0; i < 4; ++i) {
                int rl = (w << 5) + (rt << 4) + (quad << 2) + i;
                int cl = (c << 4) + Lm;
                Xs[rl * LDSPAD + cl] = (_Float16)acc[rt][c][i];
            }
    __syncthreads();
#pragma unroll
    for (int i = 0; i < 8; ++i) {
        int u = (i << 8) + tid;
        int r = u >> 4, g = u & 15;
        int row = rowbase + r;
        if (row < n) {
            uint4 v = *(uint4*)&Xs[r * LDSPAD + (g << 3)];
            *(uint4*)(h + ((size_t)row << 7) + (g << 3)) = v;
        }
    }
    int r = tid >> 1, seg = tid & 1;
    int row = rowbase + r;
    const _Float16* hp = &Xs[r * LDSPAD + (seg << 6)];
    float sa = 0.f, da = 0.f, sb = 0.f, db = 0.f;
#pragma unroll
    for (int g8 = 0; g8 < 8; ++g8) {
        half8 v = *(const half8*)&hp[g8 << 3];
        int co = (seg << 6) + (g8 << 3);
        float4 A1 = *(const float4*)&att_src[co];
        float4 A2 = *(const float4*)&att_src[co + 4];
        float4 D1 = *(const float4*)&att_dst[co];
        float4 D2 = *(const float4*)&att_dst[co + 4];
        float f0 = (float)v[0], f1 = (float)v[1], f2 = (float)v[2], f3 = (float)v[3];
        float f4 = (float)v[4], f5 = (float)v[5], f6 = (float)v[6], f7 = (float)v[7];
        float ts = f0 * A1.x + f1 * A1.y + f2 * A1.z + f3 * A1.w
                 + f4 * A2.x + f5 * A2.y + f6 * A2.z + f7 * A2.w;
        float td = f0 * D1.x + f1 * D1.y + f2 * D1.z + f3 * D1.w
                 + f4 * D2.x + f5 * D2.y + f6 * D2.z + f7 * D2.w;
        if (g8 < 4) { sa += ts; da += td; } else { sb += ts; db += td; }
    }
    if (row < n) {
        int base = (row << 2) + (seg << 1);
        a_src[base] = sa;
        a_src[base + 1] = sb;
        a_dst[base] = da;
        a_dst[base + 1] = db;
    }
}

// ---------------------------------------------------------------------------
// histogram of dst (edges only; self-loops added as +1 in scan)
__global__ void hist(const int* __restrict__ ei, const int* __restrict__ flag,
                     int* __restrict__ deg, int E) {
    int i = blockIdx.x * 256 + threadIdx.x;
    if (i >= E) return;
    int d;
    if (*flag) d = (int)((const long long*)ei)[(size_t)E + i];
    else       d = ei[(size_t)E + i];
    atomicAdd(&deg[d], 1);
}

// per-chunk sums (chunk = 2048): tot[b] = sum(deg[i]+1 for i in chunk b)
__global__ void scan_sums(const int* __restrict__ deg, int* __restrict__ tot, int n) {
    __shared__ int ts[256];
    int t = threadIdx.x;
    int i0 = (blockIdx.x << 11) + (t << 3);
    int sum = 0;
#pragma unroll
    for (int j = 0; j < 8; ++j) {
        int i = i0 + j;
        sum += (i < n) ? (deg[i] + 1) : 0;
    }
    ts[t] = sum;
    __syncthreads();
    for (int s = 128; s > 0; s >>= 1) {
        if (t < s) ts[t] += ts[t + s];
        __syncthreads();
    }
    if (t == 0) tot[blockIdx.x] = ts[0];
}

// fused chunk-base + chunk-scan + off write (+ off[n] tail)
__global__ void scan_write(const int* __restrict__ deg, const int* __restrict__ tot,
                           int* __restrict__ off, int n, int E, int nblocks) {
    __shared__ int ts[256];
    __shared__ int sbase;
    int t = threadIdx.x, bid = blockIdx.x;
    if (t < 64) {
        int v = 0;
        for (int j = t; j < bid; j += 64) v += tot[j];
        v = wred_isum(v);
        if (t == 0) sbase = v;
    }
    __syncthreads();
    int base = sbase;
    int i0 = (bid << 11) + (t << 3);
    int pref[8];
    int sum = 0;
#pragma unroll
    for (int j = 0; j < 8; ++j) {
        int i = i0 + j;
        int v = (i < n) ? (deg[i] + 1) : 0;
        pref[j] = sum;
        sum += v;
    }
    ts[t] = sum;
    __syncthreads();
    int run = sum;
    for (int d = 1; d < 256; d <<= 1) {
        int o = (t >= d) ? ts[t - d] : 0;
        __syncthreads();
        run += o;
        ts[t] = run;
        __syncthreads();
    }
    int excl = run - sum;
#pragma unroll
    for (int j = 0; j < 8; ++j) {
        int i = i0 + j;
        if (i < n) off[i] = base + excl + pref[j];
    }
    if (bid == nblocks - 1 && t == 255) off[n] = E + n;
}

// ---------------------------------------------------------------------------
// Counting-sort scatter: 4B record (src only). Alphas are computed later in
// aggregate (a_dst is wave-uniform there; a_src is an L2-resident gather).
__global__ void scatter(const int* __restrict__ ei, const int* __restrict__ flag,
                        const int* __restrict__ off, int* __restrict__ cursor,
                        int* __restrict__ sorted, int E, int n) {
    int i = blockIdx.x * 256 + threadIdx.x;
    if (i >= E + n) return;
    int s, d;
    if (i < E) {
        if (*flag) {
            s = (int)((const long long*)ei)[i];
            d = (int)((const long long*)ei)[(size_t)E + i];
        } else {
            s = ei[i];
            d = ei[(size_t)E + i];
        }
    } else {
        s = d = i - E;  // self loop
    }
    int pos = off[d] + atomicAdd(&cursor[d], 1);
    sorted[pos] = s;
}

// ---------------------------------------------------------------------------
// Gather-accumulate (fp16 h), half-wave owns 128ch: lane L=lane&31 owns ch
// 4L..4L+3 (8B/edge). Edges j = half, half+2, ...; unroll x4.
__device__ __forceinline__ void accum_half(const int* ssrc, const float* sal,
                                           const __half* __restrict__ h,
                                           int deg, int half, int L, int head,
                                           float4& acc) {
    float4 a0 = {0, 0, 0, 0}, a1 = {0, 0, 0, 0}, a2 = {0, 0, 0, 0}, a3 = {0, 0, 0, 0};
    int j = half;
    for (; j + 6 < deg; j += 8) {
        int s0 = ssrc[j], s1 = ssrc[j + 2], s2 = ssrc[j + 4], s3 = ssrc[j + 6];
        float w0 = sal[(j << 2) + head];
        float w1 = sal[((j + 2) << 2) + head];
        float w2 = sal[((j + 4) << 2) + head];
        float w3 = sal[((j + 6) << 2) + head];
        uint2 u0 = *(const uint2*)(h + ((size_t)s0 << 7) + (L << 2));
        uint2 u1 = *(const uint2*)(h + ((size_t)s1 << 7) + (L << 2));
        uint2 u2 = *(const uint2*)(h + ((size_t)s2 << 7) + (L << 2));
        uint2 u3 = *(const uint2*)(h + ((size_t)s3 << 7) + (L << 2));
        float2 f0a = unpack_h2(u0.x), f0b = unpack_h2(u0.y);
        float2 f1a = unpack_h2(u1.x), f1b = unpack_h2(u1.y);
        float2 f2a = unpack_h2(u2.x), f2b = unpack_h2(u2.y);
        float2 f3a = unpack_h2(u3.x), f3b = unpack_h2(u3.y);
        a0.x = fmaf(w0, f0a.x, a0.x); a0.y = fmaf(w0, f0a.y, a0.y);
        a0.z = fmaf(w0, f0b.x, a0.z); a0.w = fmaf(w0, f0b.y, a0.w);
        a1.x = fmaf(w1, f1a.x, a1.x); a1.y = fmaf(w1, f1a.y, a1.y);
        a1.z = fmaf(w1, f1b.x, a1.z); a1.w = fmaf(w1, f1b.y, a1.w);
        a2.x = fmaf(w2, f2a.x, a2.x); a2.y = fmaf(w2, f2a.y, a2.y);
        a2.z = fmaf(w2, f2b.x, a2.z); a2.w = fmaf(w2, f2b.y, a2.w);
        a3.x = fmaf(w3, f3a.x, a3.x); a3.y = fmaf(w3, f3a.y, a3.y);
        a3.z = fmaf(w3, f3b.x, a3.z); a3.w = fmaf(w3, f3b.y, a3.w);
    }
    for (; j < deg; j += 2) {
        int s0 = ssrc[j];
        float w0 = sal[(j << 2) + head];
        uint2 u0 = *(const uint2*)(h + ((size_t)s0 << 7) + (L << 2));
        float2 f0a = unpack_h2(u0.x), f0b = unpack_h2(u0.y);
        a0.x = fmaf(w0, f0a.x, a0.x); a0.y = fmaf(w0, f0a.y, a0.y);
        a0.z = fmaf(w0, f0b.x, a0.z); a0.w = fmaf(w0, f0b.y, a0.w);
    }
    acc.x += a0.x + a1.x + a2.x + a3.x;
    acc.y += a0.y + a1.y + a2.y + a3.y;
    acc.z += a0.z + a1.z + a2.z + a3.z;
    acc.w += a0.w + a1.w + a2.w + a3.w;
}

// One wave per destination node. Staging: lane-per-edge src read + a_src
// gather + alpha=exp(lrelu(.)) in fp32 -> LDS. Normalization deferred to
// epilogue.
__global__ __launch_bounds__(256) void aggregate(const __half* __restrict__ h,
                                                 const int* __restrict__ sorted,
                                                 const int* __restrict__ off,
                                                 const float* __restrict__ a_src,
                                                 const float* __restrict__ a_dst,
                                                 const float* __restrict__ bias,
                                                 __half* __restrict__ agg, int n) {
    __shared__ __align__(16) int sh_src[4][64];
    __shared__ __align__(16) float sh_al[4][256];    // [edge][head]
    int wslot = threadIdx.x >> 6;
    int lane = threadIdx.x & 63;
    int wid = blockIdx.x * 4 + wslot;
    int nw = gridDim.x * 4;
    int L = lane & 31, half = lane >> 5, head = L >> 3;
    float4 b4 = ((const float4*)bias)[L];
    const float4* as4 = (const float4*)a_src;
    const float4* ad4 = (const float4*)a_dst;
    int* ssrc = sh_src[wslot];
    float* sal = sh_al[wslot];

    for (int node = wid; node < n; node += nw) {
        int start = off[node], end = off[node + 1];
        int deg = end - start;          // >= 1 (self loop)
        float4 ad = ad4[node];
        float4 acc = {0.f, 0.f, 0.f, 0.f};
        float4 psum = {0.f, 0.f, 0.f, 0.f};

        if (deg <= 64) {
            bool v = lane < deg;
            int idx = start + (v ? lane : 0);
            int s = sorted[idx];
            float4 as = as4[s];
            float4 p;
            p.x = v ? __expf(lrelu(as.x + ad.x)) : 0.f;
            p.y = v ? __expf(lrelu(as.y + ad.y)) : 0.f;
            p.z = v ? __expf(lrelu(as.z + ad.z)) : 0.f;
            p.w = v ? __expf(lrelu(as.w + ad.w)) : 0.f;
            psum = p;
            ssrc[lane] = s;
            *(float4*)&sal[lane << 2] = p;
            asm volatile("s_waitcnt lgkmcnt(0)" ::: "memory");
            accum_half(ssrc, sal, h, deg, half, L, head, acc);
            asm volatile("" ::: "memory");
        } else {
            // chunked path (rare)
            for (int bb = 0; bb < deg; bb += 64) {
                int i = bb + lane;
                bool v = i < deg;
                int idx = start + (v ? i : 0);
                int s = sorted[idx];
                float4 as = as4[s];
                float4 p;
                p.x = v ? __expf(lrelu(as.x + ad.x)) : 0.f;
                p.y = v ? __expf(lrelu(as.y + ad.y)) : 0.f;
                p.z = v ? __expf(lrelu(as.z + ad.z)) : 0.f;
                p.w = v ? __expf(lrelu(as.w + ad.w)) : 0.f;
                psum.x += p.x; psum.y += p.y; psum.z += p.z; psum.w += p.w;
                ssrc[lane] = s;
                *(float4*)&sal[lane << 2] = p;
                asm volatile("s_waitcnt lgkmcnt(0)" ::: "memory");
                int cl = deg - bb;
                if (cl > 64) cl = 64;
                accum_half(ssrc, sal, h, cl, half, L, head, acc);
                asm volatile("" ::: "memory");
            }
        }
        float s0 = wred_sum(psum.x), s1 = wred_sum(psum.y);
        float s2 = wred_sum(psum.z), s3 = wred_sum(psum.w);
        float sh = (head == 0) ? s0 : (head == 1) ? s1 : (head == 2) ? s2 : s3;
        float inv = 1.f / sh;
        acc.x += __shfl_xor(acc.x, 32);
        acc.y += __shfl_xor(acc.y, 32);
        acc.z += __shfl_xor(acc.z, 32);
        acc.w += __shfl_xor(acc.w, 32);
        if (lane < 32) {
            float4 res = {fmaf(acc.x, inv, b4.x), fmaf(acc.y, inv, b4.y),
                          fmaf(acc.z, inv, b4.z), fmaf(acc.w, inv, b4.w)};
            uint2 u;
            u.x = pack_h2(res.x, res.y);
            u.y = pack_h2(res.z, res.w);
            *(uint2*)(agg + ((size_t)node << 7) + (L << 2)) = u;
        }
    }
}

// ---------------------------------------------------------------------------
// out[n][32] = elu(agg[n][128] (fp16) @ W_lin^T + b_lin)
__global__ __launch_bounds__(256) void proj(const __half* __restrict__ agg,
                                            const float* __restrict__ W_lin,
                                            const float* __restrict__ b_lin,
                                            float* __restrict__ out, int n) {
    __shared__ float xs[64][132];
    __shared__ float wt[128][36];   // wt[k][o]
    int tid = threadIdx.x;
    const float4* w4 = (const float4*)W_lin;
#pragma unroll
    for (int i = 0; i < 4; ++i) {
        int f4 = (i << 8) + tid;          // 0..1023
        int o = f4 >> 5, kk = (f4 & 31) << 2;
        float4 w = w4[f4];
        wt[kk][o] = w.x;
        wt[kk + 1][o] = w.y;
        wt[kk + 2][o] = w.z;
        wt[kk + 3][o] = w.w;
    }
    int rowbase = blockIdx.x << 6;
    const uint4* a4 = (const uint4*)agg;   // 8 halves per uint4; 16 per row
#pragma unroll
    for (int i = 0; i < 4; ++i) {
        int f8 = (i << 8) + tid;          // 0..1023
        int r = f8 >> 4, cc = (f8 & 15) << 3;
        int row = rowbase + r;
        if (row >= n) row = n - 1;
        uint4 u = a4[((size_t)row << 4) + (cc >> 3)];
        float2 f0 = unpack_h2(u.x), f1 = unpack_h2(u.y);
        float2 f2 = unpack_h2(u.z), f3 = unpack_h2(u.w);
        float* xp = &xs[r][cc];
        xp[0] = f0.x; xp[1] = f0.y; xp[2] = f1.x; xp[3] = f1.y;
        xp[4] = f2.x; xp[5] = f2.y; xp[6] = f3.x; xp[7] = f3.y;
    }
    __syncthreads();
    int r = tid >> 2, cg = tid & 3, c0 = cg << 3;
    float acc[8];
#pragma unroll
    for (int j = 0; j < 8; ++j) acc[j] = 0.f;
    for (int k = 0; k < 128; k += 4) {
        float4 xv = *(const float4*)&xs[r][k];
        float xk[4] = {xv.x, xv.y, xv.z, xv.w};
#pragma unroll
        for (int kk = 0; kk < 4; ++kk) {
            float4 wa = *(const float4*)&wt[k + kk][c0];
            float4 wb = *(const float4*)&wt[k + kk][c0 + 4];
            acc[0] = fmaf(xk[kk], wa.x, acc[0]);
            acc[1] = fmaf(xk[kk], wa.y, acc[1]);
            acc[2] = fmaf(xk[kk], wa.z, acc[2]);
            acc[3] = fmaf(xk[kk], wa.w, acc[3]);
            acc[4] = fmaf(xk[kk], wb.x, acc[4]);
            acc[5] = fmaf(xk[kk], wb.y, acc[5]);
            acc[6] = fmaf(xk[kk], wb.z, acc[6]);
            acc[7] = fmaf(xk[kk], wb.w, acc[7]);
        }
    }
    int row = rowbase + r;
    if (row < n) {
        float res[8];
#pragma unroll
        for (int j = 0; j < 8; ++j) {
            float v = acc[j] + b_lin[c0 + j];
            res[j] = v > 0.f ? v : (__expf(v) - 1.f);
        }
        float4* op = (float4*)(out + (size_t)row * 32 + c0);
        op[0] = make_float4(res[0], res[1], res[2], res[3]);
        op[1] = make_float4(res[4], res[5], res[6], res[7]);
    }
}

// ---------------------------------------------------------------------------
extern "C" void kernel_launch(void* const* d_in, const int* in_sizes, int n_in,
                              void* d_out, int out_size, void* d_ws, size_t ws_size,
                              hipStream_t stream) {
    const float* x = (const float*)d_in[0];
    const int* ei = (const int*)d_in[1];
    const float* W = (const float*)d_in[2];
    const float* att_src = (const float*)d_in[3];
    const float* att_dst = (const float*)d_in[4];
    const float* bias_conv = (const float*)d_in[5];
    const float* W_lin = (const float*)d_in[6];
    const float* b_lin = (const float*)d_in[7];
    int n = in_sizes[0] / IN_CH;
    int E = in_sizes[1] / 2;

    char* ws = (char*)d_ws;
    size_t o = 0;
    auto alloc = [&](size_t bytes) { char* p = ws + o; o = align256(o + bytes); return p; };
    __half* h      = (__half*)alloc((size_t)n * HC * 2);
    __half* agg    = (__half*)alloc((size_t)n * HC * 2);
    _Float16* wh   = (_Float16*)alloc(128 * 128 * 2);
    float* a_src   = (float*)alloc((size_t)n * NHEADS * 4);
    float* a_dst   = (float*)alloc((size_t)n * NHEADS * 4);
    int* deg       = (int*)alloc((size_t)n * 4);
    int* cursor    = (int*)alloc((size_t)n * 4);
    int* off       = (int*)alloc(((size_t)n + 1) * 4);
    int* tot       = (int*)alloc(256 * 4);
    int* flag      = (int*)alloc(256);
    int* sorted    = (int*)alloc((size_t)(E + n + 64) * 4);

    // deg and cursor are adjacent in the workspace: one memset covers both
    hipMemsetAsync(deg, 0, (size_t)((char*)cursor + (size_t)n * 4 - (char*)deg), stream);

    dw<<<65, 256, 0, stream>>>(W, wh, ei, flag);
    gemm_h<<<(n + 127) / 128, 256, 0, stream>>>(x, wh, att_src, att_dst, h, a_src, a_dst, n);
    hist<<<(E + 255) / 256, 256, 0, stream>>>(ei, flag, deg, E);
    int nchunks = (n + 2047) / 2048;
    scan_sums<<<nchunks, 256, 0, stream>>>(deg, tot, n);
    scan_write<<<nchunks, 256, 0, stream>>>(deg, tot, off, n, E, nchunks);
    scatter<<<(E + n + 255) / 256, 256, 0, stream>>>(ei, flag, off, cursor, sorted, E, n);
    aggregate<<<2048, 256, 0, stream>>>(h, sorted, off, a_src, a_dst, bias_conv, agg, n);
    proj<<<(n + 63) / 64, 256, 0, stream>>>(agg, W_lin, b_lin, (float*)d_out, n);
}

// Round 7
// 309.595 us; speedup vs baseline: 1.6251x; 1.2815x over previous
//
#include <hip/hip_runtime.h>
#include <hip/hip_fp16.h>
#include <cstdint>
#include <cstddef>

#define NHEADS 4
#define OUT_C 32
#define HC 128          // NHEADS*OUT_C
#define IN_CH 128
#define NEG_SLOPE 0.2f
#define LDSPAD 136      // halves per LDS row (128 + 8 pad)
#define KEDGE 4096      // edges per bscatter block (16/thread)

typedef _Float16 half8 __attribute__((ext_vector_type(8)));
typedef float floatx4 __attribute__((ext_vector_type(4)));

static inline size_t align256(size_t v) { return (v + 255) & ~(size_t)255; }

__device__ __forceinline__ float lrelu(float v) { return v > 0.f ? v : NEG_SLOPE * v; }

__device__ __forceinline__ float wred_sum(float v) {
    v += __shfl_xor(v, 1);
    v += __shfl_xor(v, 2);
    v += __shfl_xor(v, 4);
    v += __shfl_xor(v, 8);
    v += __shfl_xor(v, 16);
    v += __shfl_xor(v, 32);
    return v;
}

__device__ __forceinline__ unsigned int pack_h2(float a, float b) {
    __half2 h = __floats2half2_rn(a, b);
    return *reinterpret_cast<unsigned int*>(&h);
}
__device__ __forceinline__ float2 unpack_h2(unsigned int u) {
    __half2 h = *reinterpret_cast<__half2*>(&u);
    return __half22float2(h);
}

// ---------------------------------------------------------------------------
// Fused: blocks 0..63 convert W fp32->fp16; block 64 detects edge dtype
// (int64 <=> odd 4B words of first 1024 entries all zero).
__global__ void dw(const float* __restrict__ W, _Float16* __restrict__ wh,
                   const int* __restrict__ ei, int* __restrict__ flag) {
    if (blockIdx.x < 64) {
        int idx = blockIdx.x * 256 + threadIdx.x;
        wh[idx] = (_Float16)W[idx];
        return;
    }
    __shared__ int red[256];
    int t = threadIdx.x;
    int acc = 0;
    for (int i = t; i < 1024; i += 256) acc |= ei[2 * i + 1];
    red[t] = acc;
    __syncthreads();
    for (int s = 128; s > 0; s >>= 1) {
        if (t < s) red[t] |= red[t + s];
        __syncthreads();
    }
    if (t == 0) *flag = (red[0] == 0) ? 1 : 0;
}

// ---------------------------------------------------------------------------
// h[n][128] (fp16) = x[n][128] @ W^T via MFMA 16x16x32 f16 (fp32 accum).
// 128x128 tile/block, 4 waves. Fused epilogue: coalesced h store + attention
// logits a_src/a_dst.
__global__ __launch_bounds__(256) void gemm_h(const float* __restrict__ x,
                                              const _Float16* __restrict__ wh,
                                              const float* __restrict__ att_src,
                                              const float* __restrict__ att_dst,
                                              __half* __restrict__ h,
                                              float* __restrict__ a_src,
                                              float* __restrict__ a_dst, int n) {
    __shared__ __align__(16) _Float16 Ws[128 * LDSPAD];
    __shared__ __align__(16) _Float16 Xs[128 * LDSPAD];   // reused as h-tile
    int tid = threadIdx.x;
    int rowbase = blockIdx.x << 7;

    const uint4* w4 = (const uint4*)wh;
#pragma unroll
    for (int i = 0; i < 8; ++i) {
        int u = (i << 8) + tid;
        int r = u >> 4, g = u & 15;
        uint4 v = w4[u];
        *(uint4*)&Ws[r * LDSPAD + (g << 3)] = v;
    }
    const float4* x4 = (const float4*)x;
#pragma unroll
    for (int i = 0; i < 16; ++i) {
        int u = (i << 8) + tid;
        int r = u >> 5, c4 = u & 31;
        int row = rowbase + r;
        if (row >= n) row = n - 1;
        float4 v = x4[((size_t)row << 5) + c4];
        uint2 uu;
        uu.x = pack_h2(v.x, v.y);
        uu.y = pack_h2(v.z, v.w);
        *(uint2*)&Xs[r * LDSPAD + (c4 << 2)] = uu;
    }
    __syncthreads();

    int lane = tid & 63, w = tid >> 6;
    int quad = lane >> 4, Lm = lane & 15;
    floatx4 acc[2][8];
#pragma unroll
    for (int rt = 0; rt < 2; ++rt)
#pragma unroll
        for (int c = 0; c < 8; ++c) acc[rt][c] = (floatx4){0.f, 0.f, 0.f, 0.f};

#pragma unroll
    for (int kc = 0; kc < 128; kc += 32) {
        int ko = kc + (quad << 3);
        half8 a0 = *(const half8*)&Xs[((w << 5) + Lm) * LDSPAD + ko];
        half8 a1 = *(const half8*)&Xs[((w << 5) + 16 + Lm) * LDSPAD + ko];
#pragma unroll
        for (int c = 0; c < 8; ++c) {
            half8 b = *(const half8*)&Ws[((c << 4) + Lm) * LDSPAD + ko];
            acc[0][c] = __builtin_amdgcn_mfma_f32_16x16x32_f16(a0, b, acc[0][c], 0, 0, 0);
            acc[1][c] = __builtin_amdgcn_mfma_f32_16x16x32_f16(a1, b, acc[1][c], 0, 0, 0);
        }
    }
    __syncthreads();
#pragma unroll
    for (int rt = 0; rt < 2; ++rt)
#pragma unroll
        for (int c = 0; c < 8; ++c)
#pragma unroll
            for (int i = 0; i < 4; ++i) {
                int rl = (w << 5) + (rt << 4) + (quad << 2) + i;
                int cl = (c << 4) + Lm;
                Xs[rl * LDSPAD + cl] = (_Float16)acc[rt][c][i];
            }
    __syncthreads();
#pragma unroll
    for (int i = 0; i < 8; ++i) {
        int u = (i << 8) + tid;
        int r = u >> 4, g = u & 15;
        int row = rowbase + r;
        if (row < n) {
            uint4 v = *(uint4*)&Xs[r * LDSPAD + (g << 3)];
            *(uint4*)(h + ((size_t)row << 7) + (g << 3)) = v;
        }
    }
    int r = tid >> 1, seg = tid & 1;
    int row = rowbase + r;
    const _Float16* hp = &Xs[r * LDSPAD + (seg << 6)];
    float sa = 0.f, da = 0.f, sb = 0.f, db = 0.f;
#pragma unroll
    for (int g8 = 0; g8 < 8; ++g8) {
        half8 v = *(const half8*)&hp[g8 << 3];
        int co = (seg << 6) + (g8 << 3);
        float4 A1 = *(const float4*)&att_src[co];
        float4 A2 = *(const float4*)&att_src[co + 4];
        float4 D1 = *(const float4*)&att_dst[co];
        float4 D2 = *(const float4*)&att_dst[co + 4];
        float f0 = (float)v[0], f1 = (float)v[1], f2 = (float)v[2], f3 = (float)v[3];
        float f4 = (float)v[4], f5 = (float)v[5], f6 = (float)v[6], f7 = (float)v[7];
        float ts = f0 * A1.x + f1 * A1.y + f2 * A1.z + f3 * A1.w
                 + f4 * A2.x + f5 * A2.y + f6 * A2.z + f7 * A2.w;
        float td = f0 * D1.x + f1 * D1.y + f2 * D1.z + f3 * D1.w
                 + f4 * D2.x + f5 * D2.y + f6 * D2.z + f7 * D2.w;
        if (g8 < 4) { sa += ts; da += td; } else { sb += ts; db += td; }
    }
    if (row < n) {
        int base = (row << 2) + (seg << 1);
        a_src[base] = sa;
        a_src[base + 1] = sb;
        a_dst[base] = da;
        a_dst[base + 1] = db;
    }
}

// ---------------------------------------------------------------------------
// Bucket histogram over real edges (buckets of 2^sh nodes; self-loop counts
// are added analytically in bscan). LDS-staged -> 256 global atomics/block.
__global__ void bhist(const int* __restrict__ ei, const int* __restrict__ flag,
                      int* __restrict__ bcount, int E, int sh) {
    __shared__ int c[256];
    int t = threadIdx.x;
    c[t] = 0;
    __syncthreads();
    int f64 = *flag;
    int stride = gridDim.x * 256;
    for (int i = blockIdx.x * 256 + t; i < E; i += stride) {
        int d;
        if (f64) d = (int)((const long long*)ei)[(size_t)E + i];
        else     d = ei[(size_t)E + i];
        atomicAdd(&c[d >> sh], 1);
    }
    __syncthreads();
    if (c[t]) atomicAdd(&bcount[t], c[t]);
}

// ---------------------------------------------------------------------------
// Scan 256 bucket counts (+analytic self-loops) -> bucket_base[257], init
// gcursor, write off[n].
__global__ void bscan(const int* __restrict__ bcount, int* __restrict__ bucket_base,
                      int* __restrict__ gcursor, int* __restrict__ off,
                      int n, int E, int sh) {
    __shared__ int ts[256];
    int t = threadIdx.x;
    int lo = t << sh, hi = (t + 1) << sh;
    if (hi > n) hi = n;
    int nodes = hi > lo ? hi - lo : 0;
    int v = bcount[t] + nodes;
    ts[t] = v;
    __syncthreads();
    int run = v;
    for (int d = 1; d < 256; d <<= 1) {
        int o = (t >= d) ? ts[t - d] : 0;
        __syncthreads();
        run += o;
        ts[t] = run;
        __syncthreads();
    }
    int excl = run - v;
    bucket_base[t] = excl;
    gcursor[t] = excl;
    if (t == 255) {
        bucket_base[256] = run;   // == E + n
        off[n] = E + n;
    }
}

// ---------------------------------------------------------------------------
// Pass A: bucket scatter. Each block owns KEDGE edge ids (incl. self-loops at
// E..E+n), histograms by bucket in LDS, reserves contiguous per-bucket ranges
// (one global atomic per bucket per block), writes (dst,src) grouped by
// bucket -> each 64B line has a single writer block (write amp ~1x).
__global__ __launch_bounds__(256) void bscatter(const int* __restrict__ ei,
                                                const int* __restrict__ flag,
                                                int* __restrict__ gcursor,
                                                int2* __restrict__ bkt,
                                                int E, int n, int sh) {
    __shared__ int cnt[256], base[256], lcur[256];
    int t = threadIdx.x;
    cnt[t] = 0;
    lcur[t] = 0;
    int total = E + n;
    int i0 = blockIdx.x * KEDGE;
    int f64 = *flag;
    int ed[16], es[16];
    __syncthreads();
#pragma unroll
    for (int j = 0; j < 16; ++j) {
        int i = i0 + (j << 8) + t;
        int s = 0, d = -1;
        if (i < total) {
            if (i < E) {
                if (f64) {
                    s = (int)((const long long*)ei)[i];
                    d = (int)((const long long*)ei)[(size_t)E + i];
                } else {
                    s = ei[i];
                    d = ei[(size_t)E + i];
                }
            } else {
                s = d = i - E;
            }
            atomicAdd(&cnt[d >> sh], 1);
        }
        ed[j] = d;
        es[j] = s;
    }
    __syncthreads();
    base[t] = cnt[t] ? atomicAdd(&gcursor[t], cnt[t]) : 0;
    __syncthreads();
#pragma unroll
    for (int j = 0; j < 16; ++j) {
        int d = ed[j];
        if (d >= 0) {
            int b = d >> sh;
            int pos = base[b] + atomicAdd(&lcur[b], 1);
            bkt[pos] = make_int2(d, es[j]);
        }
    }
}

// ---------------------------------------------------------------------------
// Pass B: one block per bucket. Per-node histogram + block scan (emits off[])
// then in-bucket scatter of src ids; random writes span <40KB -> one XCD L2.
__global__ __launch_bounds__(256) void bsort(const int2* __restrict__ bkt,
                                             const int* __restrict__ bucket_base,
                                             int* __restrict__ off,
                                             int* __restrict__ sorted,
                                             int n, int sh) {
    __shared__ int cnt[512], offl[512], ts[256];
    int t = threadIdx.x, bid = blockIdx.x;
    int node0 = bid << sh;
    int node1 = (bid + 1) << sh;
    if (node1 > n) node1 = n;
    int nn = node1 - node0;
    int e0 = bucket_base[bid], e1 = bucket_base[bid + 1];
    cnt[t] = 0;
    cnt[t + 256] = 0;
    __syncthreads();
    for (int i = e0 + t; i < e1; i += 256) {
        int2 e = bkt[i];
        atomicAdd(&cnt[e.x - node0], 1);
    }
    __syncthreads();
    int a = cnt[t << 1], b = cnt[(t << 1) + 1];
    int s = a + b;
    ts[t] = s;
    __syncthreads();
    int run = s;
    for (int d = 1; d < 256; d <<= 1) {
        int o = (t >= d) ? ts[t - d] : 0;
        __syncthreads();
        run += o;
        ts[t] = run;
        __syncthreads();
    }
    int excl = run - s;
    offl[t << 1] = excl;
    offl[(t << 1) + 1] = excl + a;
    cnt[t << 1] = 0;
    cnt[(t << 1) + 1] = 0;
    __syncthreads();
    for (int i = t; i < nn; i += 256) off[node0 + i] = e0 + offl[i];
    for (int i = e0 + t; i < e1; i += 256) {
        int2 e = bkt[i];
        int li = e.x - node0;
        int pos = e0 + offl[li] + atomicAdd(&cnt[li], 1);
        sorted[pos] = e.y;
    }
}

// ---------------------------------------------------------------------------
// Gather-accumulate (fp16 h), half-wave owns 128ch: lane L=lane&31 owns ch
// 4L..4L+3 (8B/edge). Edges j = half, half+2, ...; unroll x4.
__device__ __forceinline__ void accum_half(const int* ssrc, const float* sal,
                                           const __half* __restrict__ h,
                                           int deg, int half, int L, int head,
                                           float4& acc) {
    float4 a0 = {0, 0, 0, 0}, a1 = {0, 0, 0, 0}, a2 = {0, 0, 0, 0}, a3 = {0, 0, 0, 0};
    int j = half;
    for (; j + 6 < deg; j += 8) {
        int s0 = ssrc[j], s1 = ssrc[j + 2], s2 = ssrc[j + 4], s3 = ssrc[j + 6];
        float w0 = sal[(j << 2) + head];
        float w1 = sal[((j + 2) << 2) + head];
        float w2 = sal[((j + 4) << 2) + head];
        float w3 = sal[((j + 6) << 2) + head];
        uint2 u0 = *(const uint2*)(h + ((size_t)s0 << 7) + (L << 2));
        uint2 u1 = *(const uint2*)(h + ((size_t)s1 << 7) + (L << 2));
        uint2 u2 = *(const uint2*)(h + ((size_t)s2 << 7) + (L << 2));
        uint2 u3 = *(const uint2*)(h + ((size_t)s3 << 7) + (L << 2));
        float2 f0a = unpack_h2(u0.x), f0b = unpack_h2(u0.y);
        float2 f1a = unpack_h2(u1.x), f1b = unpack_h2(u1.y);
        float2 f2a = unpack_h2(u2.x), f2b = unpack_h2(u2.y);
        float2 f3a = unpack_h2(u3.x), f3b = unpack_h2(u3.y);
        a0.x = fmaf(w0, f0a.x, a0.x); a0.y = fmaf(w0, f0a.y, a0.y);
        a0.z = fmaf(w0, f0b.x, a0.z); a0.w = fmaf(w0, f0b.y, a0.w);
        a1.x = fmaf(w1, f1a.x, a1.x); a1.y = fmaf(w1, f1a.y, a1.y);
        a1.z = fmaf(w1, f1b.x, a1.z); a1.w = fmaf(w1, f1b.y, a1.w);
        a2.x = fmaf(w2, f2a.x, a2.x); a2.y = fmaf(w2, f2a.y, a2.y);
        a2.z = fmaf(w2, f2b.x, a2.z); a2.w = fmaf(w2, f2b.y, a2.w);
        a3.x = fmaf(w3, f3a.x, a3.x); a3.y = fmaf(w3, f3a.y, a3.y);
        a3.z = fmaf(w3, f3b.x, a3.z); a3.w = fmaf(w3, f3b.y, a3.w);
    }
    for (; j < deg; j += 2) {
        int s0 = ssrc[j];
        float w0 = sal[(j << 2) + head];
        uint2 u0 = *(const uint2*)(h + ((size_t)s0 << 7) + (L << 2));
        float2 f0a = unpack_h2(u0.x), f0b = unpack_h2(u0.y);
        a0.x = fmaf(w0, f0a.x, a0.x); a0.y = fmaf(w0, f0a.y, a0.y);
        a0.z = fmaf(w0, f0b.x, a0.z); a0.w = fmaf(w0, f0b.y, a0.w);
    }
    acc.x += a0.x + a1.x + a2.x + a3.x;
    acc.y += a0.y + a1.y + a2.y + a3.y;
    acc.z += a0.z + a1.z + a2.z + a3.z;
    acc.w += a0.w + a1.w + a2.w + a3.w;
}

// One wave per destination node. Staging: lane-per-edge src read + a_src
// gather + alpha=exp(lrelu(.)) in fp32 -> LDS. Normalization deferred to
// epilogue.
__global__ __launch_bounds__(256) void aggregate(const __half* __restrict__ h,
                                                 const int* __restrict__ sorted,
                                                 const int* __restrict__ off,
                                                 const float* __restrict__ a_src,
                                                 const float* __restrict__ a_dst,
                                                 const float* __restrict__ bias,
                                                 __half* __restrict__ agg, int n) {
    __shared__ __align__(16) int sh_src[4][64];
    __shared__ __align__(16) float sh_al[4][256];    // [edge][head]
    int wslot = threadIdx.x >> 6;
    int lane = threadIdx.x & 63;
    int wid = blockIdx.x * 4 + wslot;
    int nw = gridDim.x * 4;
    int L = lane & 31, half = lane >> 5, head = L >> 3;
    float4 b4 = ((const float4*)bias)[L];
    const float4* as4 = (const float4*)a_src;
    const float4* ad4 = (const float4*)a_dst;
    int* ssrc = sh_src[wslot];
    float* sal = sh_al[wslot];

    for (int node = wid; node < n; node += nw) {
        int start = off[node], end = off[node + 1];
        int deg = end - start;          // >= 1 (self loop)
        float4 ad = ad4[node];
        float4 acc = {0.f, 0.f, 0.f, 0.f};
        float4 psum = {0.f, 0.f, 0.f, 0.f};

        if (deg <= 64) {
            bool v = lane < deg;
            int idx = start + (v ? lane : 0);
            int s = sorted[idx];
            float4 as = as4[s];
            float4 p;
            p.x = v ? __expf(lrelu(as.x + ad.x)) : 0.f;
            p.y = v ? __expf(lrelu(as.y + ad.y)) : 0.f;
            p.z = v ? __expf(lrelu(as.z + ad.z)) : 0.f;
            p.w = v ? __expf(lrelu(as.w + ad.w)) : 0.f;
            psum = p;
            ssrc[lane] = s;
            *(float4*)&sal[lane << 2] = p;
            asm volatile("s_waitcnt lgkmcnt(0)" ::: "memory");
            accum_half(ssrc, sal, h, deg, half, L, head, acc);
            asm volatile("" ::: "memory");
        } else {
            // chunked path (rare)
            for (int bb = 0; bb < deg; bb += 64) {
                int i = bb + lane;
                bool v = i < deg;
                int idx = start + (v ? i : 0);
                int s = sorted[idx];
                float4 as = as4[s];
                float4 p;
                p.x = v ? __expf(lrelu(as.x + ad.x)) : 0.f;
                p.y = v ? __expf(lrelu(as.y + ad.y)) : 0.f;
                p.z = v ? __expf(lrelu(as.z + ad.z)) : 0.f;
                p.w = v ? __expf(lrelu(as.w + ad.w)) : 0.f;
                psum.x += p.x; psum.y += p.y; psum.z += p.z; psum.w += p.w;
                ssrc[lane] = s;
                *(float4*)&sal[lane << 2] = p;
                asm volatile("s_waitcnt lgkmcnt(0)" ::: "memory");
                int cl = deg - bb;
                if (cl > 64) cl = 64;
                accum_half(ssrc, sal, h, cl, half, L, head, acc);
                asm volatile("" ::: "memory");
            }
        }
        float s0 = wred_sum(psum.x), s1 = wred_sum(psum.y);
        float s2 = wred_sum(psum.z), s3 = wred_sum(psum.w);
        float sh = (head == 0) ? s0 : (head == 1) ? s1 : (head == 2) ? s2 : s3;
        float inv = 1.f / sh;
        acc.x += __shfl_xor(acc.x, 32);
        acc.y += __shfl_xor(acc.y, 32);
        acc.z += __shfl_xor(acc.z, 32);
        acc.w += __shfl_xor(acc.w, 32);
        if (lane < 32) {
            float4 res = {fmaf(acc.x, inv, b4.x), fmaf(acc.y, inv, b4.y),
                          fmaf(acc.z, inv, b4.z), fmaf(acc.w, inv, b4.w)};
            uint2 u;
            u.x = pack_h2(res.x, res.y);
            u.y = pack_h2(res.z, res.w);
            *(uint2*)(agg + ((size_t)node << 7) + (L << 2)) = u;
        }
    }
}

// ---------------------------------------------------------------------------
// out[n][32] = elu(agg[n][128] (fp16) @ W_lin^T + b_lin)
__global__ __launch_bounds__(256) void proj(const __half* __restrict__ agg,
                                            const float* __restrict__ W_lin,
                                            const float* __restrict__ b_lin,
                                            float* __restrict__ out, int n) {
    __shared__ float xs[64][132];
    __shared__ float wt[128][36];   // wt[k][o]
    int tid = threadIdx.x;
    const float4* w4 = (const float4*)W_lin;
#pragma unroll
    for (int i = 0; i < 4; ++i) {
        int f4 = (i << 8) + tid;          // 0..1023
        int o = f4 >> 5, kk = (f4 & 31) << 2;
        float4 w = w4[f4];
        wt[kk][o] = w.x;
        wt[kk + 1][o] = w.y;
        wt[kk + 2][o] = w.z;
        wt[kk + 3][o] = w.w;
    }
    int rowbase = blockIdx.x << 6;
    const uint4* a4 = (const uint4*)agg;   // 8 halves per uint4; 16 per row
#pragma unroll
    for (int i = 0; i < 4; ++i) {
        int f8 = (i << 8) + tid;          // 0..1023
        int r = f8 >> 4, cc = (f8 & 15) << 3;
        int row = rowbase + r;
        if (row >= n) row = n - 1;
        uint4 u = a4[((size_t)row << 4) + (cc >> 3)];
        float2 f0 = unpack_h2(u.x), f1 = unpack_h2(u.y);
        float2 f2 = unpack_h2(u.z), f3 = unpack_h2(u.w);
        float* xp = &xs[r][cc];
        xp[0] = f0.x; xp[1] = f0.y; xp[2] = f1.x; xp[3] = f1.y;
        xp[4] = f2.x; xp[5] = f2.y; xp[6] = f3.x; xp[7] = f3.y;
    }
    __syncthreads();
    int r = tid >> 2, cg = tid & 3, c0 = cg << 3;
    float acc[8];
#pragma unroll
    for (int j = 0; j < 8; ++j) acc[j] = 0.f;
    for (int k = 0; k < 128; k += 4) {
        float4 xv = *(const float4*)&xs[r][k];
        float xk[4] = {xv.x, xv.y, xv.z, xv.w};
#pragma unroll
        for (int kk = 0; kk < 4; ++kk) {
            float4 wa = *(const float4*)&wt[k + kk][c0];
            float4 wb = *(const float4*)&wt[k + kk][c0 + 4];
            acc[0] = fmaf(xk[kk], wa.x, acc[0]);
            acc[1] = fmaf(xk[kk], wa.y, acc[1]);
            acc[2] = fmaf(xk[kk], wa.z, acc[2]);
            acc[3] = fmaf(xk[kk], wa.w, acc[3]);
            acc[4] = fmaf(xk[kk], wb.x, acc[4]);
            acc[5] = fmaf(xk[kk], wb.y, acc[5]);
            acc[6] = fmaf(xk[kk], wb.z, acc[6]);
            acc[7] = fmaf(xk[kk], wb.w, acc[7]);
        }
    }
    int row = rowbase + r;
    if (row < n) {
        float res[8];
#pragma unroll
        for (int j = 0; j < 8; ++j) {
            float v = acc[j] + b_lin[c0 + j];
            res[j] = v > 0.f ? v : (__expf(v) - 1.f);
        }
        float4* op = (float4*)(out + (size_t)row * 32 + c0);
        op[0] = make_float4(res[0], res[1], res[2], res[3]);
        op[1] = make_float4(res[4], res[5], res[6], res[7]);
    }
}

// ---------------------------------------------------------------------------
extern "C" void kernel_launch(void* const* d_in, const int* in_sizes, int n_in,
                              void* d_out, int out_size, void* d_ws, size_t ws_size,
                              hipStream_t stream) {
    const float* x = (const float*)d_in[0];
    const int* ei = (const int*)d_in[1];
    const float* W = (const float*)d_in[2];
    const float* att_src = (const float*)d_in[3];
    const float* att_dst = (const float*)d_in[4];
    const float* bias_conv = (const float*)d_in[5];
    const float* W_lin = (const float*)d_in[6];
    const float* b_lin = (const float*)d_in[7];
    int n = in_sizes[0] / IN_CH;
    int E = in_sizes[1] / 2;

    // bucket shift: smallest sh with ceil(n/2^sh) <= 256 (and 2^sh <= 512 for
    // this problem size; n=100000 -> sh=9, NB=196)
    int sh = 0;
    while (((n + (1 << sh) - 1) >> sh) > 256) sh++;
    int NB = (n + (1 << sh) - 1) >> sh;

    char* ws = (char*)d_ws;
    size_t o = 0;
    auto alloc = [&](size_t bytes) { char* p = ws + o; o = align256(o + bytes); return p; };
    __half* h        = (__half*)alloc((size_t)n * HC * 2);
    __half* agg      = (__half*)alloc((size_t)n * HC * 2);
    _Float16* wh     = (_Float16*)alloc(128 * 128 * 2);
    float* a_src     = (float*)alloc((size_t)n * NHEADS * 4);
    float* a_dst     = (float*)alloc((size_t)n * NHEADS * 4);
    int* off         = (int*)alloc(((size_t)n + 1) * 4);
    int* bcount      = (int*)alloc(256 * 4);
    int* bucket_base = (int*)alloc(257 * 4);
    int* gcursor     = (int*)alloc(256 * 4);
    int* flag        = (int*)alloc(256);
    int* sorted      = (int*)alloc((size_t)(E + n + 64) * 4);
    int2* bkt        = (int2*)alloc((size_t)(E + n + 64) * 8);

    hipMemsetAsync(bcount, 0, 256 * 4, stream);

    dw<<<65, 256, 0, stream>>>(W, wh, ei, flag);
    gemm_h<<<(n + 127) / 128, 256, 0, stream>>>(x, wh, att_src, att_dst, h, a_src, a_dst, n);
    bhist<<<1024, 256, 0, stream>>>(ei, flag, bcount, E, sh);
    bscan<<<1, 256, 0, stream>>>(bcount, bucket_base, gcursor, off, n, E, sh);
    bscatter<<<(E + n + KEDGE - 1) / KEDGE, 256, 0, stream>>>(ei, flag, gcursor, bkt, E, n, sh);
    bsort<<<NB, 256, 0, stream>>>(bkt, bucket_base, off, sorted, n, sh);
    aggregate<<<2048, 256, 0, stream>>>(h, sorted, off, a_src, a_dst, bias_conv, agg, n);
    proj<<<(n + 63) / 64, 256, 0, stream>>>(agg, W_lin, b_lin, (float*)d_out, n);
}